// Round 14
// baseline (301.999 us; speedup 1.0000x reference)
//
#include <hip/hip_runtime.h>
#include <hip/hip_bf16.h>
#include <stdint.h>

#define T_SEQ   2048
#define D_MODEL 1024
#define NHEAD   16
#define DHEAD   64
#define BATCH   4
#define MTOK    (BATCH * T_SEQ)   // 8192

typedef __attribute__((ext_vector_type(4))) float f32x4;
typedef __attribute__((ext_vector_type(16))) float f32x16;
typedef __attribute__((ext_vector_type(8))) short bf16x8;
typedef __attribute__((ext_vector_type(4))) short s16x4;
typedef __attribute__((ext_vector_type(4))) unsigned u32x4;
typedef __attribute__((ext_vector_type(2))) unsigned u32x2;

__device__ __forceinline__ f32x4 mfma16(bf16x8 a, bf16x8 b, f32x4 c) {
  return __builtin_amdgcn_mfma_f32_16x16x32_bf16(a, b, c, 0, 0, 0);
}
__device__ __forceinline__ f32x16 mfma32(bf16x8 a, bf16x8 b, f32x16 c) {
  return __builtin_amdgcn_mfma_f32_32x32x16_bf16(a, b, c, 0, 0, 0);
}

__device__ __forceinline__ short f2bf(float f) {
  __hip_bfloat16 h = __float2bfloat16(f);
  return *reinterpret_cast<short*>(&h);
}

// v_cvt_pk_bf16_f32: dst = {lo16: bf16(a), hi16: bf16(b)} (no builtin on gfx950)
__device__ __forceinline__ unsigned cvtpk(float a, float b) {
  unsigned r;
  asm("v_cvt_pk_bf16_f32 %0, %1, %2" : "=v"(r) : "v"(a), "v"(b));
  return r;
}

// permlane32_swap via the INTRINSIC (T12 recipe): returns the pair
//   r[0] = {a.row0, b.row0},  r[1] = {a.row1, b.row1}.
// Round-11 lesson: the raw "+v","+v" inline-asm form is unsafe when both
// operands carry the same value (LLVM coalesces them into ONE register ->
// v_permlane32_swap_b32 v5,v5 scrambles rows instead of exchanging) -> NaN.
__device__ __forceinline__ u32x2 plswap(unsigned a, unsigned b) {
  return __builtin_amdgcn_permlane32_swap(a, b, false, false);
}

union PB { u32x4 u; bf16x8 b; };

#define GLD_LDS16(gp, lp)                                                      \
  __builtin_amdgcn_global_load_lds(                                            \
      (const __attribute__((address_space(1))) void*)(gp),                     \
      (__attribute__((address_space(3))) void*)(lp), 16, 0, 0)

// ---------------------------------------------------------------------------
// Weight transpose + fp32->bf16 convert: Wt[n][k] = W[k][n], 4 weights
// ---------------------------------------------------------------------------
__global__ __launch_bounds__(256) void transpose_w_kernel(
    const float* __restrict__ W0, const float* __restrict__ W1,
    const float* __restrict__ W2, const float* __restrict__ W3,
    short* __restrict__ out)
{
  const int z = blockIdx.z;
  const float* W = (z == 0) ? W0 : (z == 1) ? W1 : (z == 2) ? W2 : W3;
  short* o = out + (size_t)z * D_MODEL * D_MODEL;
  __shared__ float tile[32][33];
  const int n0 = blockIdx.x * 32, k0 = blockIdx.y * 32;
  const int c = threadIdx.x & 31, r = threadIdx.x >> 5;
#pragma unroll
  for (int i = 0; i < 4; i++)
    tile[r + i * 8][c] = W[(size_t)(k0 + r + i * 8) * D_MODEL + n0 + c];
  __syncthreads();
#pragma unroll
  for (int i = 0; i < 4; i++)
    o[(size_t)(n0 + r + i * 8) * D_MODEL + k0 + c] = f2bf(tile[c][r + i * 8]);
}

// ---------------------------------------------------------------------------
// x fp32 -> bf16 (8 elements / thread)
// ---------------------------------------------------------------------------
__global__ __launch_bounds__(256) void cvt_x_kernel(
    const float* __restrict__ x, short* __restrict__ xb)
{
  const size_t i = (size_t)blockIdx.x * 256 + threadIdx.x;
  const float4 a = ((const float4*)x)[i * 2];
  const float4 b = ((const float4*)x)[i * 2 + 1];
  bf16x8 o;
  o[0] = f2bf(a.x); o[1] = f2bf(a.y); o[2] = f2bf(a.z); o[3] = f2bf(a.w);
  o[4] = f2bf(b.x); o[5] = f2bf(b.y); o[6] = f2bf(b.z); o[7] = f2bf(b.w);
  ((bf16x8*)xb)[i] = o;
}

// ---------------------------------------------------------------------------
// GEMM: C[M][1024] = A[M][1024](bf16) * Bt[1024][1024]^T(bf16, N-major) + bias
// (final WO projection; fp32 out)
// ---------------------------------------------------------------------------
__global__ __launch_bounds__(256) void gemm_bt(
    const short* __restrict__ A, const short* __restrict__ Bt,
    const float* __restrict__ bias, float* __restrict__ Cp)
{
  __shared__ __align__(16) short As[128 * 32];
  __shared__ __align__(16) short Bs[128 * 32];
  const int tid = threadIdx.x, lane = tid & 63, wid = tid >> 6;
  const int wr = wid >> 1, wc = wid & 1;
  const int lg = lane >> 4, ln = lane & 15;
  const int m0 = blockIdx.x * 128, n0 = blockIdx.y * 128;
  const int lrow = lane >> 2, lchunk = lane & 3;

  f32x4 acc[4][4];
#pragma unroll
  for (int i = 0; i < 4; i++)
#pragma unroll
    for (int j = 0; j < 4; j++) acc[i][j] = {0.f, 0.f, 0.f, 0.f};

  for (int k0 = 0; k0 < 1024; k0 += 32) {
#pragma unroll
    for (int s = 0; s < 2; ++s) {
      const int rbase = (wid * 2 + s) * 16;
      const short* gpa = A + (size_t)(m0 + rbase + lrow) * 1024 + k0 + lchunk * 8;
      GLD_LDS16(gpa, As + rbase * 32);
      const short* gpb = Bt + (size_t)(n0 + rbase + lrow) * 1024 + k0 + lchunk * 8;
      GLD_LDS16(gpb, Bs + rbase * 32);
    }
    __syncthreads();
    bf16x8 a[4], b[4];
#pragma unroll
    for (int mi = 0; mi < 4; mi++)
      a[mi] = *(const bf16x8*)(As + (wr * 64 + mi * 16 + ln) * 32 + lg * 8);
#pragma unroll
    for (int ni = 0; ni < 4; ni++)
      b[ni] = *(const bf16x8*)(Bs + (wc * 64 + ni * 16 + ln) * 32 + lg * 8);
#pragma unroll
    for (int mi = 0; mi < 4; mi++)
#pragma unroll
      for (int ni = 0; ni < 4; ni++)
        acc[mi][ni] = mfma16(a[mi], b[ni], acc[mi][ni]);
    __syncthreads();
  }

#pragma unroll
  for (int mi = 0; mi < 4; mi++)
#pragma unroll
    for (int ni = 0; ni < 4; ni++)
#pragma unroll
      for (int r = 0; r < 4; r++) {
        const int row = m0 + wr * 64 + mi * 16 + lg * 4 + r;
        const int col = n0 + wc * 64 + ni * 16 + ln;
        Cp[(size_t)row * 1024 + col] = acc[mi][ni][r] + bias[col];
      }
}

// ---------------------------------------------------------------------------
// Fused QKV GEMM: Wt is the contiguous [3072][1024] concat of WQt/WKt/WVt.
// One dispatch (grid 64x24). Q scaled by 0.125*log2e. V segment written
// directly in Vt[b][h][dh][t] layout (round 13 - deletes transpose_v).
// ---------------------------------------------------------------------------
__global__ __launch_bounds__(256) void gemm_qkv(
    const short* __restrict__ A, const short* __restrict__ Wt,
    const float* __restrict__ bQ, const float* __restrict__ bK,
    const float* __restrict__ bV,
    short* __restrict__ Qb, short* __restrict__ Kb, short* __restrict__ Vt,
    float qscale)
{
  __shared__ __align__(16) short As[128 * 32];
  __shared__ __align__(16) short Bs[128 * 32];
  const int tid = threadIdx.x, lane = tid & 63, wid = tid >> 6;
  const int wr = wid >> 1, wc = wid & 1;
  const int lg = lane >> 4, ln = lane & 15;
  const int m0 = blockIdx.x * 128;
  const int nglob = blockIdx.y * 128;          // 0..3071
  const int seg = blockIdx.y >> 3;             // 0=Q 1=K 2=V
  const int n0 = nglob & 1023;
  const short* Bt = Wt + (size_t)nglob * 1024; // concat rows are n-major
  const float* bias = (seg == 0) ? bQ : (seg == 1) ? bK : bV;
  const float scale = (seg == 0) ? qscale : 1.0f;
  const int lrow = lane >> 2, lchunk = lane & 3;

  f32x4 acc[4][4];
#pragma unroll
  for (int i = 0; i < 4; i++)
#pragma unroll
    for (int j = 0; j < 4; j++) acc[i][j] = {0.f, 0.f, 0.f, 0.f};

  for (int k0 = 0; k0 < 1024; k0 += 32) {
#pragma unroll
    for (int s = 0; s < 2; ++s) {
      const int rbase = (wid * 2 + s) * 16;
      const short* gpa = A + (size_t)(m0 + rbase + lrow) * 1024 + k0 + lchunk * 8;
      GLD_LDS16(gpa, As + rbase * 32);
      const short* gpb = Bt + (size_t)(rbase + lrow) * 1024 + k0 + lchunk * 8;
      GLD_LDS16(gpb, Bs + rbase * 32);
    }
    __syncthreads();
    bf16x8 a[4], b[4];
#pragma unroll
    for (int mi = 0; mi < 4; mi++)
      a[mi] = *(const bf16x8*)(As + (wr * 64 + mi * 16 + ln) * 32 + lg * 8);
#pragma unroll
    for (int ni = 0; ni < 4; ni++)
      b[ni] = *(const bf16x8*)(Bs + (wc * 64 + ni * 16 + ln) * 32 + lg * 8);
#pragma unroll
    for (int mi = 0; mi < 4; mi++)
#pragma unroll
      for (int ni = 0; ni < 4; ni++)
        acc[mi][ni] = mfma16(a[mi], b[ni], acc[mi][ni]);
    __syncthreads();
  }

  if (seg == 2) {
    // direct Vt[b][h][dh][t] write: 8B per (mi,ni)
    const int bb = m0 >> 11;                   // batch, constant per block
    const int tbase = (m0 & 2047) + wr * 64 + lg * 4;
#pragma unroll
    for (int mi = 0; mi < 4; mi++)
#pragma unroll
      for (int ni = 0; ni < 4; ni++) {
        const int col = n0 + wc * 64 + ni * 16 + ln;
        const int hh = col >> 6, dh = col & 63;
        s16x4 w;
#pragma unroll
        for (int r = 0; r < 4; r++) w[r] = f2bf(acc[mi][ni][r] + bias[col]);
        *(s16x4*)(Vt + (size_t)((bb * 16 + hh) * 64 + dh) * T_SEQ +
                  tbase + mi * 16) = w;
      }
  } else {
    short* Cp = (seg == 0) ? Qb : Kb;
#pragma unroll
    for (int mi = 0; mi < 4; mi++)
#pragma unroll
      for (int ni = 0; ni < 4; ni++)
#pragma unroll
        for (int r = 0; r < 4; r++) {
          const int row = m0 + wr * 64 + mi * 16 + lg * 4 + r;
          const int col = n0 + wc * 64 + ni * 16 + ln;
          const float v = (acc[mi][ni][r] + bias[col]) * scale;
          Cp[(size_t)row * 1024 + col] = f2bf(v);
        }
  }
}

// ---------------------------------------------------------------------------
// Causal flash attention v12: single-chain waves, 4096 waves = 4/SIMD.
// Round-14 insight: VGPR 120 <= 128 means HW can host 4 waves/SIMD; the
// dual-chain pairing only provided 2048 waves. Dropping the pairing (one
// 32-row q-tile per wave, same tile_chain) doubles TLP with INDEPENDENT
// program counters (dual-chain's 2 chains share one PC - a stall blocks
// both). State drops (~-48 VGPR) so __launch_bounds__(256,4) fits.
// Balance: block s=id>>6 hosts classes {s,31-s,32+s,63-s} rotated by
// (wid+(s>>2))&3 -> per-block work constant, each SIMD gets a mixed set.
// ---------------------------------------------------------------------------
__device__ __forceinline__ void tile_chain(
    const bf16x8* kf0, const bf16x8* kf1,
    const bf16x8* vf0, const bf16x8* vf1,
    const bf16x8* qf, const f32x16& zv,
    f32x16& o0, f32x16& o1, float& m_run, float& l_run,
    const int kv0, const int qw, const int q, const int hi)
{
  f32x16 s0, s1;
  __builtin_amdgcn_s_setprio(1);
  s0 = mfma32(kf0[0], qf[0], zv);
#pragma unroll
  for (int c = 1; c < 4; c++) s0 = mfma32(kf0[c], qf[c], s0);
  s1 = mfma32(kf1[0], qf[0], zv);
#pragma unroll
  for (int c = 1; c < 4; c++) s1 = mfma32(kf1[c], qf[c], s1);
  __builtin_amdgcn_s_setprio(0);

  if (kv0 + 63 > qw) {
    const int qrel = q - kv0 - 4 * hi;
#pragma unroll
    for (int r = 0; r < 16; r++) {
      const int cst = (r & 3) + 8 * (r >> 2);
      if (cst > qrel) s0[r] = -3.0e38f;
      if (cst + 32 > qrel) s1[r] = -3.0e38f;
    }
  }

  float mx;
  {
    float t[8];
#pragma unroll
    for (int i = 0; i < 8; i++)
      t[i] = fmaxf(fmaxf(s0[i], s0[i + 8]), fmaxf(s1[i], s1[i + 8]));
    const float a0 = fmaxf(fmaxf(t[0], t[1]), fmaxf(t[2], t[3]));
    const float a1 = fmaxf(fmaxf(t[4], t[5]), fmaxf(t[6], t[7]));
    mx = fmaxf(a0, a1);
    u32x2 r = plswap(__float_as_uint(mx), __float_as_uint(mx));
    mx = fmaxf(__uint_as_float(r[0]), __uint_as_float(r[1]));
  }
  // T13 defer-max: only rescale when the max grew by > 8 (wave-uniform).
  if (!__all(mx - m_run <= 8.0f)) {
    const float mn = fmaxf(m_run, mx);
    const float rr = exp2f(m_run - mn);
    m_run = mn;
    l_run *= rr;
#pragma unroll
    for (int i = 0; i < 16; i++) { o0[i] *= rr; o1[i] *= rr; }
  }
  const float mn = m_run;
#pragma unroll
  for (int i = 0; i < 16; i++) s0[i] = exp2f(s0[i] - mn);
#pragma unroll
  for (int i = 0; i < 16; i++) s1[i] = exp2f(s1[i] - mn);
  float ts;
  {
    float t[8];
#pragma unroll
    for (int i = 0; i < 8; i++) t[i] = (s0[i] + s0[i + 8]) + (s1[i] + s1[i + 8]);
    ts = ((t[0] + t[1]) + (t[2] + t[3])) + ((t[4] + t[5]) + (t[6] + t[7]));
    u32x2 r = plswap(__float_as_uint(ts), __float_as_uint(ts));
    ts = __uint_as_float(r[0]) + __uint_as_float(r[1]);
  }
  l_run += ts;

  // P -> PV B-fragments: cvt_pk pairs + permlane32 half-exchange.
  PB pb[4];
  {
    unsigned c0 = cvtpk(s0[0], s0[1]),   c1 = cvtpk(s0[2], s0[3]);
    unsigned c2 = cvtpk(s0[4], s0[5]),   c3 = cvtpk(s0[6], s0[7]);
    unsigned c4 = cvtpk(s0[8], s0[9]),   c5 = cvtpk(s0[10], s0[11]);
    unsigned c6 = cvtpk(s0[12], s0[13]), c7 = cvtpk(s0[14], s0[15]);
    u32x2 r02 = plswap(c0, c2), r13 = plswap(c1, c3);
    u32x2 r46 = plswap(c4, c6), r57 = plswap(c5, c7);
    pb[0].u = (u32x4){r02[0], r13[0], r02[1], r13[1]};
    pb[1].u = (u32x4){r46[0], r57[0], r46[1], r57[1]};
  }
  {
    unsigned c0 = cvtpk(s1[0], s1[1]),   c1 = cvtpk(s1[2], s1[3]);
    unsigned c2 = cvtpk(s1[4], s1[5]),   c3 = cvtpk(s1[6], s1[7]);
    unsigned c4 = cvtpk(s1[8], s1[9]),   c5 = cvtpk(s1[10], s1[11]);
    unsigned c6 = cvtpk(s1[12], s1[13]), c7 = cvtpk(s1[14], s1[15]);
    u32x2 r02 = plswap(c0, c2), r13 = plswap(c1, c3);
    u32x2 r46 = plswap(c4, c6), r57 = plswap(c5, c7);
    pb[2].u = (u32x4){r02[0], r13[0], r02[1], r13[1]};
    pb[3].u = (u32x4){r46[0], r57[0], r46[1], r57[1]};
  }

  __builtin_amdgcn_s_setprio(1);
#pragma unroll
  for (int kc = 0; kc < 4; kc++) {
    o0 = mfma32(vf0[kc], pb[kc].b, o0);
    o1 = mfma32(vf1[kc], pb[kc].b, o1);
  }
  __builtin_amdgcn_s_setprio(0);
}

__device__ __forceinline__ void attn_epilogue(
    short* cp, const f32x16& o0, const f32x16& o1, float l_run, int hi)
{
  const float inv = 1.0f / l_run;
#pragma unroll
  for (int g = 0; g < 4; g++) {
    s16x4 w0, w1;
#pragma unroll
    for (int j = 0; j < 4; j++) {
      w0[j] = f2bf(o0[g * 4 + j] * inv);   // dh = g*8 + 4*hi + j
      w1[j] = f2bf(o1[g * 4 + j] * inv);   // dh = 32 + g*8 + 4*hi + j
    }
    *(s16x4*)(cp + g * 8 + 4 * hi) = w0;
    *(s16x4*)(cp + 32 + g * 8 + 4 * hi) = w1;
  }
}

__global__ __launch_bounds__(256, 4) void attn_fwd(
    const short* __restrict__ Q, const short* __restrict__ K,
    const short* __restrict__ Vt, short* __restrict__ ctx)
{
  const int tid = threadIdx.x, lane = tid & 63, wid = tid >> 6;
  const int hi = lane >> 5, lq = lane & 31;
  // XCD swizzle: id&7 = XCD; the 16 blocks of one bh share an XCD's L2.
  const int id = (int)blockIdx.x;
  const int bh = (id & 7) * 8 + ((id >> 3) & 7);
  const int s = id >> 6;                        // 0..15
  const int b = bh >> 4, h = bh & 15;

  // class rotation: per-block all 4 classes; co-resident blocks differ in
  // s>>2 mod 4 -> each SIMD hosts a {short,med,med,long} mix.
  const int cls = (wid + (s >> 2)) & 3;
  const int qt = (cls == 0) ? s : (cls == 1) ? (31 - s)
               : (cls == 2) ? (32 + s) : (63 - s);
  const int qw = qt * 32;
  const int q = qw + lq;

  bf16x8 qf[4];
  {
    const short* qp = Q + (size_t)(b * T_SEQ + q) * 1024 + h * 64 + hi * 8;
#pragma unroll
    for (int c = 0; c < 4; c++) qf[c] = *(const bf16x8*)(qp + c * 16);
  }

  f32x16 zv;
#pragma unroll
  for (int i = 0; i < 16; i++) zv[i] = 0.f;

  f32x16 o0 = zv, o1 = zv;
  float m_run = -3.0e38f, l_run = 0.f;

  const int nt = (qw + 95) >> 6;

#pragma unroll 1
  for (int it = 0; it < nt; ++it) {
    const int kv0 = it * 64;
    bf16x8 kf0[4], kf1[4], vf0[4], vf1[4];
    {
      const short* kp = K + (size_t)(b * T_SEQ + kv0 + lq) * 1024 + h * 64 + hi * 8;
      const short* vp = Vt + (size_t)(bh * 64 + lq) * T_SEQ + kv0 + hi * 8;
#pragma unroll
      for (int c = 0; c < 4; c++) {
        kf0[c] = *(const bf16x8*)(kp + c * 16);
        kf1[c] = *(const bf16x8*)(kp + 32 * 1024 + c * 16);
        vf0[c] = *(const bf16x8*)(vp + c * 16);
        vf1[c] = *(const bf16x8*)(vp + 32 * T_SEQ + c * 16);
      }
    }
    tile_chain(kf0, kf1, vf0, vf1, qf, zv, o0, o1, m_run, l_run, kv0, qw, q, hi);
  }

  attn_epilogue(ctx + (size_t)(b * T_SEQ + q) * 1024 + h * 64, o0, o1, l_run, hi);
}

// ---------------------------------------------------------------------------
extern "C" void kernel_launch(void* const* d_in, const int* in_sizes, int n_in,
                              void* d_out, int out_size, void* d_ws, size_t ws_size,
                              hipStream_t stream)
{
  (void)in_sizes; (void)n_in; (void)out_size; (void)ws_size;
  const float* x  = (const float*)d_in[0];
  // d_in[1] = causal mask (triu, k=1) — structure is known, not read
  const float* WQ = (const float*)d_in[2];
  const float* bQ = (const float*)d_in[3];
  const float* WK = (const float*)d_in[4];
  const float* bK = (const float*)d_in[5];
  const float* WV = (const float*)d_in[6];
  const float* bV = (const float*)d_in[7];
  const float* WO = (const float*)d_in[8];
  const float* bO = (const float*)d_in[9];
  float* out = (float*)d_out;

  const size_t MB = 1024ull * 1024ull;
  char* w = (char*)d_ws;
  short* xb = (short*)(w);             // 16MB; reused as ctx after QKV GEMMs
  short* Wt = (short*)(w + 16 * MB);   // 8MB: WQt,WKt,WVt,WOt bf16 (contiguous)
  short* Qb = (short*)(w + 24 * MB);   // 16MB
  short* Kb = (short*)(w + 40 * MB);   // 16MB
  short* Vt = (short*)(w + 72 * MB);   // 16MB (written directly by gemm_qkv)
  short* ctx = xb;

  transpose_w_kernel<<<dim3(32, 32, 4), 256, 0, stream>>>(WQ, WK, WV, WO, Wt);
  cvt_x_kernel<<<dim3(MTOK * D_MODEL / 8 / 256), 256, 0, stream>>>(x, xb);

  const float qscale = 0.125f * 1.4426950408889634f;  // fold 1/sqrt(64) * log2(e)
  gemm_qkv<<<dim3(64, 24), 256, 0, stream>>>(xb, Wt, bQ, bK, bV, Qb, Kb, Vt, qscale);

  attn_fwd<<<dim3(1024), 256, 0, stream>>>(Qb, Kb, Vt, ctx);

  gemm_bt<<<dim3(64, 8), 256, 0, stream>>>(ctx, Wt + 3ull * D_MODEL * D_MODEL, bO, out);
}

// Round 15
// 265.194 us; speedup vs baseline: 1.1388x; 1.1388x over previous
//
#include <hip/hip_runtime.h>
#include <hip/hip_bf16.h>
#include <stdint.h>

#define T_SEQ   2048
#define D_MODEL 1024
#define NHEAD   16
#define DHEAD   64
#define BATCH   4
#define MTOK    (BATCH * T_SEQ)   // 8192

typedef __attribute__((ext_vector_type(4))) float f32x4;
typedef __attribute__((ext_vector_type(16))) float f32x16;
typedef __attribute__((ext_vector_type(8))) short bf16x8;
typedef __attribute__((ext_vector_type(4))) short s16x4;
typedef __attribute__((ext_vector_type(4))) unsigned u32x4;
typedef __attribute__((ext_vector_type(2))) unsigned u32x2;

__device__ __forceinline__ f32x4 mfma16(bf16x8 a, bf16x8 b, f32x4 c) {
  return __builtin_amdgcn_mfma_f32_16x16x32_bf16(a, b, c, 0, 0, 0);
}
__device__ __forceinline__ f32x16 mfma32(bf16x8 a, bf16x8 b, f32x16 c) {
  return __builtin_amdgcn_mfma_f32_32x32x16_bf16(a, b, c, 0, 0, 0);
}

__device__ __forceinline__ short f2bf(float f) {
  __hip_bfloat16 h = __float2bfloat16(f);
  return *reinterpret_cast<short*>(&h);
}

// v_cvt_pk_bf16_f32: dst = {lo16: bf16(a), hi16: bf16(b)} (no builtin on gfx950)
__device__ __forceinline__ unsigned cvtpk(float a, float b) {
  unsigned r;
  asm("v_cvt_pk_bf16_f32 %0, %1, %2" : "=v"(r) : "v"(a), "v"(b));
  return r;
}

// permlane32_swap via the INTRINSIC (T12 recipe): returns the pair
//   r[0] = {a.row0, b.row0},  r[1] = {a.row1, b.row1}.
// Round-11 lesson: the raw "+v","+v" inline-asm form is unsafe when both
// operands carry the same value (LLVM coalesces them into ONE register ->
// v_permlane32_swap_b32 v5,v5 scrambles rows instead of exchanging) -> NaN.
__device__ __forceinline__ u32x2 plswap(unsigned a, unsigned b) {
  return __builtin_amdgcn_permlane32_swap(a, b, false, false);
}

union PB { u32x4 u; bf16x8 b; };

#define GLD_LDS16(gp, lp)                                                      \
  __builtin_amdgcn_global_load_lds(                                            \
      (const __attribute__((address_space(1))) void*)(gp),                     \
      (__attribute__((address_space(3))) void*)(lp), 16, 0, 0)

// ---------------------------------------------------------------------------
// Weight transpose + fp32->bf16 convert: Wt[n][k] = W[k][n], 4 weights
// ---------------------------------------------------------------------------
__global__ __launch_bounds__(256) void transpose_w_kernel(
    const float* __restrict__ W0, const float* __restrict__ W1,
    const float* __restrict__ W2, const float* __restrict__ W3,
    short* __restrict__ out)
{
  const int z = blockIdx.z;
  const float* W = (z == 0) ? W0 : (z == 1) ? W1 : (z == 2) ? W2 : W3;
  short* o = out + (size_t)z * D_MODEL * D_MODEL;
  __shared__ float tile[32][33];
  const int n0 = blockIdx.x * 32, k0 = blockIdx.y * 32;
  const int c = threadIdx.x & 31, r = threadIdx.x >> 5;
#pragma unroll
  for (int i = 0; i < 4; i++)
    tile[r + i * 8][c] = W[(size_t)(k0 + r + i * 8) * D_MODEL + n0 + c];
  __syncthreads();
#pragma unroll
  for (int i = 0; i < 4; i++)
    o[(size_t)(n0 + r + i * 8) * D_MODEL + k0 + c] = f2bf(tile[c][r + i * 8]);
}

// ---------------------------------------------------------------------------
// x fp32 -> bf16 (8 elements / thread)
// ---------------------------------------------------------------------------
__global__ __launch_bounds__(256) void cvt_x_kernel(
    const float* __restrict__ x, short* __restrict__ xb)
{
  const size_t i = (size_t)blockIdx.x * 256 + threadIdx.x;
  const float4 a = ((const float4*)x)[i * 2];
  const float4 b = ((const float4*)x)[i * 2 + 1];
  bf16x8 o;
  o[0] = f2bf(a.x); o[1] = f2bf(a.y); o[2] = f2bf(a.z); o[3] = f2bf(a.w);
  o[4] = f2bf(b.x); o[5] = f2bf(b.y); o[6] = f2bf(b.z); o[7] = f2bf(b.w);
  ((bf16x8*)xb)[i] = o;
}

// ---------------------------------------------------------------------------
// GEMM: C[M][1024] = A[M][1024](bf16) * Bt[1024][1024]^T(bf16, N-major) + bias
// (final WO projection; fp32 out)
// ---------------------------------------------------------------------------
__global__ __launch_bounds__(256) void gemm_bt(
    const short* __restrict__ A, const short* __restrict__ Bt,
    const float* __restrict__ bias, float* __restrict__ Cp)
{
  __shared__ __align__(16) short As[128 * 32];
  __shared__ __align__(16) short Bs[128 * 32];
  const int tid = threadIdx.x, lane = tid & 63, wid = tid >> 6;
  const int wr = wid >> 1, wc = wid & 1;
  const int lg = lane >> 4, ln = lane & 15;
  const int m0 = blockIdx.x * 128, n0 = blockIdx.y * 128;
  const int lrow = lane >> 2, lchunk = lane & 3;

  f32x4 acc[4][4];
#pragma unroll
  for (int i = 0; i < 4; i++)
#pragma unroll
    for (int j = 0; j < 4; j++) acc[i][j] = {0.f, 0.f, 0.f, 0.f};

  for (int k0 = 0; k0 < 1024; k0 += 32) {
#pragma unroll
    for (int s = 0; s < 2; ++s) {
      const int rbase = (wid * 2 + s) * 16;
      const short* gpa = A + (size_t)(m0 + rbase + lrow) * 1024 + k0 + lchunk * 8;
      GLD_LDS16(gpa, As + rbase * 32);
      const short* gpb = Bt + (size_t)(n0 + rbase + lrow) * 1024 + k0 + lchunk * 8;
      GLD_LDS16(gpb, Bs + rbase * 32);
    }
    __syncthreads();
    bf16x8 a[4], b[4];
#pragma unroll
    for (int mi = 0; mi < 4; mi++)
      a[mi] = *(const bf16x8*)(As + (wr * 64 + mi * 16 + ln) * 32 + lg * 8);
#pragma unroll
    for (int ni = 0; ni < 4; ni++)
      b[ni] = *(const bf16x8*)(Bs + (wc * 64 + ni * 16 + ln) * 32 + lg * 8);
#pragma unroll
    for (int mi = 0; mi < 4; mi++)
#pragma unroll
      for (int ni = 0; ni < 4; ni++)
        acc[mi][ni] = mfma16(a[mi], b[ni], acc[mi][ni]);
    __syncthreads();
  }

#pragma unroll
  for (int mi = 0; mi < 4; mi++)
#pragma unroll
    for (int ni = 0; ni < 4; ni++)
#pragma unroll
      for (int r = 0; r < 4; r++) {
        const int row = m0 + wr * 64 + mi * 16 + lg * 4 + r;
        const int col = n0 + wc * 64 + ni * 16 + ln;
        Cp[(size_t)row * 1024 + col] = acc[mi][ni][r] + bias[col];
      }
}

// ---------------------------------------------------------------------------
// Fused QKV GEMM: Wt is the contiguous [3072][1024] concat of WQt/WKt/WVt.
// One dispatch (grid 64x24). Q scaled by 0.125*log2e. V segment written
// directly in Vt[b][h][dh][t] layout (round 13 - deletes transpose_v).
// ---------------------------------------------------------------------------
__global__ __launch_bounds__(256) void gemm_qkv(
    const short* __restrict__ A, const short* __restrict__ Wt,
    const float* __restrict__ bQ, const float* __restrict__ bK,
    const float* __restrict__ bV,
    short* __restrict__ Qb, short* __restrict__ Kb, short* __restrict__ Vt,
    float qscale)
{
  __shared__ __align__(16) short As[128 * 32];
  __shared__ __align__(16) short Bs[128 * 32];
  const int tid = threadIdx.x, lane = tid & 63, wid = tid >> 6;
  const int wr = wid >> 1, wc = wid & 1;
  const int lg = lane >> 4, ln = lane & 15;
  const int m0 = blockIdx.x * 128;
  const int nglob = blockIdx.y * 128;          // 0..3071
  const int seg = blockIdx.y >> 3;             // 0=Q 1=K 2=V
  const int n0 = nglob & 1023;
  const short* Bt = Wt + (size_t)nglob * 1024; // concat rows are n-major
  const float* bias = (seg == 0) ? bQ : (seg == 1) ? bK : bV;
  const float scale = (seg == 0) ? qscale : 1.0f;
  const int lrow = lane >> 2, lchunk = lane & 3;

  f32x4 acc[4][4];
#pragma unroll
  for (int i = 0; i < 4; i++)
#pragma unroll
    for (int j = 0; j < 4; j++) acc[i][j] = {0.f, 0.f, 0.f, 0.f};

  for (int k0 = 0; k0 < 1024; k0 += 32) {
#pragma unroll
    for (int s = 0; s < 2; ++s) {
      const int rbase = (wid * 2 + s) * 16;
      const short* gpa = A + (size_t)(m0 + rbase + lrow) * 1024 + k0 + lchunk * 8;
      GLD_LDS16(gpa, As + rbase * 32);
      const short* gpb = Bt + (size_t)(rbase + lrow) * 1024 + k0 + lchunk * 8;
      GLD_LDS16(gpb, Bs + rbase * 32);
    }
    __syncthreads();
    bf16x8 a[4], b[4];
#pragma unroll
    for (int mi = 0; mi < 4; mi++)
      a[mi] = *(const bf16x8*)(As + (wr * 64 + mi * 16 + ln) * 32 + lg * 8);
#pragma unroll
    for (int ni = 0; ni < 4; ni++)
      b[ni] = *(const bf16x8*)(Bs + (wc * 64 + ni * 16 + ln) * 32 + lg * 8);
#pragma unroll
    for (int mi = 0; mi < 4; mi++)
#pragma unroll
      for (int ni = 0; ni < 4; ni++)
        acc[mi][ni] = mfma16(a[mi], b[ni], acc[mi][ni]);
    __syncthreads();
  }

  if (seg == 2) {
    // direct Vt[b][h][dh][t] write: 8B per (mi,ni)
    const int bb = m0 >> 11;                   // batch, constant per block
    const int tbase = (m0 & 2047) + wr * 64 + lg * 4;
#pragma unroll
    for (int mi = 0; mi < 4; mi++)
#pragma unroll
      for (int ni = 0; ni < 4; ni++) {
        const int col = n0 + wc * 64 + ni * 16 + ln;
        const int hh = col >> 6, dh = col & 63;
        s16x4 w;
#pragma unroll
        for (int r = 0; r < 4; r++) w[r] = f2bf(acc[mi][ni][r] + bias[col]);
        *(s16x4*)(Vt + (size_t)((bb * 16 + hh) * 64 + dh) * T_SEQ +
                  tbase + mi * 16) = w;
      }
  } else {
    short* Cp = (seg == 0) ? Qb : Kb;
#pragma unroll
    for (int mi = 0; mi < 4; mi++)
#pragma unroll
      for (int ni = 0; ni < 4; ni++)
#pragma unroll
        for (int r = 0; r < 4; r++) {
          const int row = m0 + wr * 64 + mi * 16 + lg * 4 + r;
          const int col = n0 + wc * 64 + ni * 16 + ln;
          const float v = (acc[mi][ni][r] + bias[col]) * scale;
          Cp[(size_t)row * 1024 + col] = f2bf(v);
        }
  }
}

// ---------------------------------------------------------------------------
// Causal flash attention v13: single-chain waves, 4096 waves, NATURAL
// register allocation. Round-14 lesson: __launch_bounds__(256,4) forced the
// allocator to 64 VGPR -> 219MB spill scratch -> regression. But round-13's
// dual-chain compiled to VGPR 120 <= 128 UNFORCED, i.e. the HW already
// permits 4 waves/SIMD at this pressure (m69 thresholds 64/128/256) - it was
// only grid-limited (2048 waves). Fix: single-chain (leaner state than
// dual-chain) + (256,2) bound (min-occupancy only, no reg cap) + 1024
// blocks. If VGPR lands <=128 the scheduler reaches 4 waves/SIMD naturally.
// Balance: block s=id>>6 hosts classes {s,31-s,32+s,63-s} rotated by
// (wid+(s>>2))&3 -> per-block work constant, each SIMD gets a mixed set.
// ---------------------------------------------------------------------------
__device__ __forceinline__ void tile_chain(
    const bf16x8* kf0, const bf16x8* kf1,
    const bf16x8* vf0, const bf16x8* vf1,
    const bf16x8* qf, const f32x16& zv,
    f32x16& o0, f32x16& o1, float& m_run, float& l_run,
    const int kv0, const int qw, const int q, const int hi)
{
  f32x16 s0, s1;
  __builtin_amdgcn_s_setprio(1);
  s0 = mfma32(kf0[0], qf[0], zv);
#pragma unroll
  for (int c = 1; c < 4; c++) s0 = mfma32(kf0[c], qf[c], s0);
  s1 = mfma32(kf1[0], qf[0], zv);
#pragma unroll
  for (int c = 1; c < 4; c++) s1 = mfma32(kf1[c], qf[c], s1);
  __builtin_amdgcn_s_setprio(0);

  if (kv0 + 63 > qw) {
    const int qrel = q - kv0 - 4 * hi;
#pragma unroll
    for (int r = 0; r < 16; r++) {
      const int cst = (r & 3) + 8 * (r >> 2);
      if (cst > qrel) s0[r] = -3.0e38f;
      if (cst + 32 > qrel) s1[r] = -3.0e38f;
    }
  }

  float mx;
  {
    float t[8];
#pragma unroll
    for (int i = 0; i < 8; i++)
      t[i] = fmaxf(fmaxf(s0[i], s0[i + 8]), fmaxf(s1[i], s1[i + 8]));
    const float a0 = fmaxf(fmaxf(t[0], t[1]), fmaxf(t[2], t[3]));
    const float a1 = fmaxf(fmaxf(t[4], t[5]), fmaxf(t[6], t[7]));
    mx = fmaxf(a0, a1);
    u32x2 r = plswap(__float_as_uint(mx), __float_as_uint(mx));
    mx = fmaxf(__uint_as_float(r[0]), __uint_as_float(r[1]));
  }
  // T13 defer-max: only rescale when the max grew by > 8 (wave-uniform).
  if (!__all(mx - m_run <= 8.0f)) {
    const float mn = fmaxf(m_run, mx);
    const float rr = exp2f(m_run - mn);
    m_run = mn;
    l_run *= rr;
#pragma unroll
    for (int i = 0; i < 16; i++) { o0[i] *= rr; o1[i] *= rr; }
  }
  const float mn = m_run;
#pragma unroll
  for (int i = 0; i < 16; i++) s0[i] = exp2f(s0[i] - mn);
#pragma unroll
  for (int i = 0; i < 16; i++) s1[i] = exp2f(s1[i] - mn);
  float ts;
  {
    float t[8];
#pragma unroll
    for (int i = 0; i < 8; i++) t[i] = (s0[i] + s0[i + 8]) + (s1[i] + s1[i + 8]);
    ts = ((t[0] + t[1]) + (t[2] + t[3])) + ((t[4] + t[5]) + (t[6] + t[7]));
    u32x2 r = plswap(__float_as_uint(ts), __float_as_uint(ts));
    ts = __uint_as_float(r[0]) + __uint_as_float(r[1]);
  }
  l_run += ts;

  // P -> PV B-fragments: cvt_pk pairs + permlane32 half-exchange.
  PB pb[4];
  {
    unsigned c0 = cvtpk(s0[0], s0[1]),   c1 = cvtpk(s0[2], s0[3]);
    unsigned c2 = cvtpk(s0[4], s0[5]),   c3 = cvtpk(s0[6], s0[7]);
    unsigned c4 = cvtpk(s0[8], s0[9]),   c5 = cvtpk(s0[10], s0[11]);
    unsigned c6 = cvtpk(s0[12], s0[13]), c7 = cvtpk(s0[14], s0[15]);
    u32x2 r02 = plswap(c0, c2), r13 = plswap(c1, c3);
    u32x2 r46 = plswap(c4, c6), r57 = plswap(c5, c7);
    pb[0].u = (u32x4){r02[0], r13[0], r02[1], r13[1]};
    pb[1].u = (u32x4){r46[0], r57[0], r46[1], r57[1]};
  }
  {
    unsigned c0 = cvtpk(s1[0], s1[1]),   c1 = cvtpk(s1[2], s1[3]);
    unsigned c2 = cvtpk(s1[4], s1[5]),   c3 = cvtpk(s1[6], s1[7]);
    unsigned c4 = cvtpk(s1[8], s1[9]),   c5 = cvtpk(s1[10], s1[11]);
    unsigned c6 = cvtpk(s1[12], s1[13]), c7 = cvtpk(s1[14], s1[15]);
    u32x2 r02 = plswap(c0, c2), r13 = plswap(c1, c3);
    u32x2 r46 = plswap(c4, c6), r57 = plswap(c5, c7);
    pb[2].u = (u32x4){r02[0], r13[0], r02[1], r13[1]};
    pb[3].u = (u32x4){r46[0], r57[0], r46[1], r57[1]};
  }

  __builtin_amdgcn_s_setprio(1);
#pragma unroll
  for (int kc = 0; kc < 4; kc++) {
    o0 = mfma32(vf0[kc], pb[kc].b, o0);
    o1 = mfma32(vf1[kc], pb[kc].b, o1);
  }
  __builtin_amdgcn_s_setprio(0);
}

__device__ __forceinline__ void attn_epilogue(
    short* cp, const f32x16& o0, const f32x16& o1, float l_run, int hi)
{
  const float inv = 1.0f / l_run;
#pragma unroll
  for (int g = 0; g < 4; g++) {
    s16x4 w0, w1;
#pragma unroll
    for (int j = 0; j < 4; j++) {
      w0[j] = f2bf(o0[g * 4 + j] * inv);   // dh = g*8 + 4*hi + j
      w1[j] = f2bf(o1[g * 4 + j] * inv);   // dh = 32 + g*8 + 4*hi + j
    }
    *(s16x4*)(cp + g * 8 + 4 * hi) = w0;
    *(s16x4*)(cp + 32 + g * 8 + 4 * hi) = w1;
  }
}

__global__ __launch_bounds__(256, 2) void attn_fwd(
    const short* __restrict__ Q, const short* __restrict__ K,
    const short* __restrict__ Vt, short* __restrict__ ctx)
{
  const int tid = threadIdx.x, lane = tid & 63, wid = tid >> 6;
  const int hi = lane >> 5, lq = lane & 31;
  // XCD swizzle: id&7 = XCD; the 16 blocks of one bh share an XCD's L2.
  const int id = (int)blockIdx.x;
  const int bh = (id & 7) * 8 + ((id >> 3) & 7);
  const int s = id >> 6;                        // 0..15
  const int b = bh >> 4, h = bh & 15;

  // class rotation: per-block all 4 classes; co-resident blocks differ in
  // s>>2 mod 4 -> each SIMD hosts a {short,med,med,long} mix.
  const int cls = (wid + (s >> 2)) & 3;
  const int qt = (cls == 0) ? s : (cls == 1) ? (31 - s)
               : (cls == 2) ? (32 + s) : (63 - s);
  const int qw = qt * 32;
  const int q = qw + lq;

  bf16x8 qf[4];
  {
    const short* qp = Q + (size_t)(b * T_SEQ + q) * 1024 + h * 64 + hi * 8;
#pragma unroll
    for (int c = 0; c < 4; c++) qf[c] = *(const bf16x8*)(qp + c * 16);
  }

  f32x16 zv;
#pragma unroll
  for (int i = 0; i < 16; i++) zv[i] = 0.f;

  f32x16 o0 = zv, o1 = zv;
  float m_run = -3.0e38f, l_run = 0.f;

  const int nt = (qw + 95) >> 6;

#pragma unroll 1
  for (int it = 0; it < nt; ++it) {
    const int kv0 = it * 64;
    bf16x8 kf0[4], kf1[4], vf0[4], vf1[4];
    {
      const short* kp = K + (size_t)(b * T_SEQ + kv0 + lq) * 1024 + h * 64 + hi * 8;
      const short* vp = Vt + (size_t)(bh * 64 + lq) * T_SEQ + kv0 + hi * 8;
#pragma unroll
      for (int c = 0; c < 4; c++) {
        kf0[c] = *(const bf16x8*)(kp + c * 16);
        kf1[c] = *(const bf16x8*)(kp + 32 * 1024 + c * 16);
        vf0[c] = *(const bf16x8*)(vp + c * 16);
        vf1[c] = *(const bf16x8*)(vp + 32 * T_SEQ + c * 16);
      }
    }
    tile_chain(kf0, kf1, vf0, vf1, qf, zv, o0, o1, m_run, l_run, kv0, qw, q, hi);
  }

  attn_epilogue(ctx + (size_t)(b * T_SEQ + q) * 1024 + h * 64, o0, o1, l_run, hi);
}

// ---------------------------------------------------------------------------
extern "C" void kernel_launch(void* const* d_in, const int* in_sizes, int n_in,
                              void* d_out, int out_size, void* d_ws, size_t ws_size,
                              hipStream_t stream)
{
  (void)in_sizes; (void)n_in; (void)out_size; (void)ws_size;
  const float* x  = (const float*)d_in[0];
  // d_in[1] = causal mask (triu, k=1) — structure is known, not read
  const float* WQ = (const float*)d_in[2];
  const float* bQ = (const float*)d_in[3];
  const float* WK = (const float*)d_in[4];
  const float* bK = (const float*)d_in[5];
  const float* WV = (const float*)d_in[6];
  const float* bV = (const float*)d_in[7];
  const float* WO = (const float*)d_in[8];
  const float* bO = (const float*)d_in[9];
  float* out = (float*)d_out;

  const size_t MB = 1024ull * 1024ull;
  char* w = (char*)d_ws;
  short* xb = (short*)(w);             // 16MB; reused as ctx after QKV GEMMs
  short* Wt = (short*)(w + 16 * MB);   // 8MB: WQt,WKt,WVt,WOt bf16 (contiguous)
  short* Qb = (short*)(w + 24 * MB);   // 16MB
  short* Kb = (short*)(w + 40 * MB);   // 16MB
  short* Vt = (short*)(w + 72 * MB);   // 16MB (written directly by gemm_qkv)
  short* ctx = xb;

  transpose_w_kernel<<<dim3(32, 32, 4), 256, 0, stream>>>(WQ, WK, WV, WO, Wt);
  cvt_x_kernel<<<dim3(MTOK * D_MODEL / 8 / 256), 256, 0, stream>>>(x, xb);

  const float qscale = 0.125f * 1.4426950408889634f;  // fold 1/sqrt(64) * log2(e)
  gemm_qkv<<<dim3(64, 24), 256, 0, stream>>>(xb, Wt, bQ, bK, bV, Qb, Kb, Vt, qscale);

  attn_fwd<<<dim3(1024), 256, 0, stream>>>(Qb, Kb, Vt, ctx);

  gemm_bt<<<dim3(64, 8), 256, 0, stream>>>(ctx, Wt + 3ull * D_MODEL * D_MODEL, bO, out);
}

// Round 16
// 242.229 us; speedup vs baseline: 1.2467x; 1.0948x over previous
//
#include <hip/hip_runtime.h>
#include <hip/hip_bf16.h>
#include <stdint.h>

#define T_SEQ   2048
#define D_MODEL 1024
#define NHEAD   16
#define DHEAD   64
#define BATCH   4
#define MTOK    (BATCH * T_SEQ)   // 8192

typedef __attribute__((ext_vector_type(4))) float f32x4;
typedef __attribute__((ext_vector_type(16))) float f32x16;
typedef __attribute__((ext_vector_type(8))) short bf16x8;
typedef __attribute__((ext_vector_type(4))) short s16x4;
typedef __attribute__((ext_vector_type(4))) unsigned u32x4;
typedef __attribute__((ext_vector_type(2))) unsigned u32x2;

__device__ __forceinline__ f32x4 mfma16(bf16x8 a, bf16x8 b, f32x4 c) {
  return __builtin_amdgcn_mfma_f32_16x16x32_bf16(a, b, c, 0, 0, 0);
}
__device__ __forceinline__ f32x16 mfma32(bf16x8 a, bf16x8 b, f32x16 c) {
  return __builtin_amdgcn_mfma_f32_32x32x16_bf16(a, b, c, 0, 0, 0);
}

__device__ __forceinline__ short f2bf(float f) {
  __hip_bfloat16 h = __float2bfloat16(f);
  return *reinterpret_cast<short*>(&h);
}

// v_cvt_pk_bf16_f32: dst = {lo16: bf16(a), hi16: bf16(b)} (no builtin on gfx950)
__device__ __forceinline__ unsigned cvtpk(float a, float b) {
  unsigned r;
  asm("v_cvt_pk_bf16_f32 %0, %1, %2" : "=v"(r) : "v"(a), "v"(b));
  return r;
}

// permlane32_swap via the INTRINSIC (T12 recipe): returns the pair
//   r[0] = {a.row0, b.row0},  r[1] = {a.row1, b.row1}.
// Round-11 lesson: the raw "+v","+v" inline-asm form is unsafe when both
// operands carry the same value (LLVM coalesces them into ONE register ->
// v_permlane32_swap_b32 v5,v5 scrambles rows instead of exchanging) -> NaN.
__device__ __forceinline__ u32x2 plswap(unsigned a, unsigned b) {
  return __builtin_amdgcn_permlane32_swap(a, b, false, false);
}

union PB { u32x4 u; bf16x8 b; };

#define GLD_LDS16(gp, lp)                                                      \
  __builtin_amdgcn_global_load_lds(                                            \
      (const __attribute__((address_space(1))) void*)(gp),                     \
      (__attribute__((address_space(3))) void*)(lp), 16, 0, 0)

// ---------------------------------------------------------------------------
// Weight transpose + fp32->bf16 convert: Wt[n][k] = W[k][n], 4 weights
// ---------------------------------------------------------------------------
__global__ __launch_bounds__(256) void transpose_w_kernel(
    const float* __restrict__ W0, const float* __restrict__ W1,
    const float* __restrict__ W2, const float* __restrict__ W3,
    short* __restrict__ out)
{
  const int z = blockIdx.z;
  const float* W = (z == 0) ? W0 : (z == 1) ? W1 : (z == 2) ? W2 : W3;
  short* o = out + (size_t)z * D_MODEL * D_MODEL;
  __shared__ float tile[32][33];
  const int n0 = blockIdx.x * 32, k0 = blockIdx.y * 32;
  const int c = threadIdx.x & 31, r = threadIdx.x >> 5;
#pragma unroll
  for (int i = 0; i < 4; i++)
    tile[r + i * 8][c] = W[(size_t)(k0 + r + i * 8) * D_MODEL + n0 + c];
  __syncthreads();
#pragma unroll
  for (int i = 0; i < 4; i++)
    o[(size_t)(n0 + r + i * 8) * D_MODEL + k0 + c] = f2bf(tile[c][r + i * 8]);
}

// ---------------------------------------------------------------------------
// x fp32 -> bf16 (8 elements / thread)
// ---------------------------------------------------------------------------
__global__ __launch_bounds__(256) void cvt_x_kernel(
    const float* __restrict__ x, short* __restrict__ xb)
{
  const size_t i = (size_t)blockIdx.x * 256 + threadIdx.x;
  const float4 a = ((const float4*)x)[i * 2];
  const float4 b = ((const float4*)x)[i * 2 + 1];
  bf16x8 o;
  o[0] = f2bf(a.x); o[1] = f2bf(a.y); o[2] = f2bf(a.z); o[3] = f2bf(a.w);
  o[4] = f2bf(b.x); o[5] = f2bf(b.y); o[6] = f2bf(b.z); o[7] = f2bf(b.w);
  ((bf16x8*)xb)[i] = o;
}

// ---------------------------------------------------------------------------
// GEMM: C[M][1024] = A[M][1024](bf16) * Bt[1024][1024]^T(bf16, N-major) + bias
// (final WO projection; fp32 out)
// ---------------------------------------------------------------------------
__global__ __launch_bounds__(256) void gemm_bt(
    const short* __restrict__ A, const short* __restrict__ Bt,
    const float* __restrict__ bias, float* __restrict__ Cp)
{
  __shared__ __align__(16) short As[128 * 32];
  __shared__ __align__(16) short Bs[128 * 32];
  const int tid = threadIdx.x, lane = tid & 63, wid = tid >> 6;
  const int wr = wid >> 1, wc = wid & 1;
  const int lg = lane >> 4, ln = lane & 15;
  const int m0 = blockIdx.x * 128, n0 = blockIdx.y * 128;
  const int lrow = lane >> 2, lchunk = lane & 3;

  f32x4 acc[4][4];
#pragma unroll
  for (int i = 0; i < 4; i++)
#pragma unroll
    for (int j = 0; j < 4; j++) acc[i][j] = {0.f, 0.f, 0.f, 0.f};

  for (int k0 = 0; k0 < 1024; k0 += 32) {
#pragma unroll
    for (int s = 0; s < 2; ++s) {
      const int rbase = (wid * 2 + s) * 16;
      const short* gpa = A + (size_t)(m0 + rbase + lrow) * 1024 + k0 + lchunk * 8;
      GLD_LDS16(gpa, As + rbase * 32);
      const short* gpb = Bt + (size_t)(n0 + rbase + lrow) * 1024 + k0 + lchunk * 8;
      GLD_LDS16(gpb, Bs + rbase * 32);
    }
    __syncthreads();
    bf16x8 a[4], b[4];
#pragma unroll
    for (int mi = 0; mi < 4; mi++)
      a[mi] = *(const bf16x8*)(As + (wr * 64 + mi * 16 + ln) * 32 + lg * 8);
#pragma unroll
    for (int ni = 0; ni < 4; ni++)
      b[ni] = *(const bf16x8*)(Bs + (wc * 64 + ni * 16 + ln) * 32 + lg * 8);
#pragma unroll
    for (int mi = 0; mi < 4; mi++)
#pragma unroll
      for (int ni = 0; ni < 4; ni++)
        acc[mi][ni] = mfma16(a[mi], b[ni], acc[mi][ni]);
    __syncthreads();
  }

#pragma unroll
  for (int mi = 0; mi < 4; mi++)
#pragma unroll
    for (int ni = 0; ni < 4; ni++)
#pragma unroll
      for (int r = 0; r < 4; r++) {
        const int row = m0 + wr * 64 + mi * 16 + lg * 4 + r;
        const int col = n0 + wc * 64 + ni * 16 + ln;
        Cp[(size_t)row * 1024 + col] = acc[mi][ni][r] + bias[col];
      }
}

// ---------------------------------------------------------------------------
// Fused QKV GEMM: Wt is the contiguous [3072][1024] concat of WQt/WKt/WVt.
// One dispatch (grid 64x24). Q scaled by 0.125*log2e. V segment written
// directly in Vt[b][h][dh][t] layout (round 13 - deletes transpose_v).
// ---------------------------------------------------------------------------
__global__ __launch_bounds__(256) void gemm_qkv(
    const short* __restrict__ A, const short* __restrict__ Wt,
    const float* __restrict__ bQ, const float* __restrict__ bK,
    const float* __restrict__ bV,
    short* __restrict__ Qb, short* __restrict__ Kb, short* __restrict__ Vt,
    float qscale)
{
  __shared__ __align__(16) short As[128 * 32];
  __shared__ __align__(16) short Bs[128 * 32];
  const int tid = threadIdx.x, lane = tid & 63, wid = tid >> 6;
  const int wr = wid >> 1, wc = wid & 1;
  const int lg = lane >> 4, ln = lane & 15;
  const int m0 = blockIdx.x * 128;
  const int nglob = blockIdx.y * 128;          // 0..3071
  const int seg = blockIdx.y >> 3;             // 0=Q 1=K 2=V
  const int n0 = nglob & 1023;
  const short* Bt = Wt + (size_t)nglob * 1024; // concat rows are n-major
  const float* bias = (seg == 0) ? bQ : (seg == 1) ? bK : bV;
  const float scale = (seg == 0) ? qscale : 1.0f;
  const int lrow = lane >> 2, lchunk = lane & 3;

  f32x4 acc[4][4];
#pragma unroll
  for (int i = 0; i < 4; i++)
#pragma unroll
    for (int j = 0; j < 4; j++) acc[i][j] = {0.f, 0.f, 0.f, 0.f};

  for (int k0 = 0; k0 < 1024; k0 += 32) {
#pragma unroll
    for (int s = 0; s < 2; ++s) {
      const int rbase = (wid * 2 + s) * 16;
      const short* gpa = A + (size_t)(m0 + rbase + lrow) * 1024 + k0 + lchunk * 8;
      GLD_LDS16(gpa, As + rbase * 32);
      const short* gpb = Bt + (size_t)(rbase + lrow) * 1024 + k0 + lchunk * 8;
      GLD_LDS16(gpb, Bs + rbase * 32);
    }
    __syncthreads();
    bf16x8 a[4], b[4];
#pragma unroll
    for (int mi = 0; mi < 4; mi++)
      a[mi] = *(const bf16x8*)(As + (wr * 64 + mi * 16 + ln) * 32 + lg * 8);
#pragma unroll
    for (int ni = 0; ni < 4; ni++)
      b[ni] = *(const bf16x8*)(Bs + (wc * 64 + ni * 16 + ln) * 32 + lg * 8);
#pragma unroll
    for (int mi = 0; mi < 4; mi++)
#pragma unroll
      for (int ni = 0; ni < 4; ni++)
        acc[mi][ni] = mfma16(a[mi], b[ni], acc[mi][ni]);
    __syncthreads();
  }

  if (seg == 2) {
    // direct Vt[b][h][dh][t] write: 8B per (mi,ni)
    const int bb = m0 >> 11;                   // batch, constant per block
    const int tbase = (m0 & 2047) + wr * 64 + lg * 4;
#pragma unroll
    for (int mi = 0; mi < 4; mi++)
#pragma unroll
      for (int ni = 0; ni < 4; ni++) {
        const int col = n0 + wc * 64 + ni * 16 + ln;
        const int hh = col >> 6, dh = col & 63;
        s16x4 w;
#pragma unroll
        for (int r = 0; r < 4; r++) w[r] = f2bf(acc[mi][ni][r] + bias[col]);
        *(s16x4*)(Vt + (size_t)((bb * 16 + hh) * 64 + dh) * T_SEQ +
                  tbase + mi * 16) = w;
      }
  } else {
    short* Cp = (seg == 0) ? Qb : Kb;
#pragma unroll
    for (int mi = 0; mi < 4; mi++)
#pragma unroll
      for (int ni = 0; ni < 4; ni++)
#pragma unroll
        for (int r = 0; r < 4; r++) {
          const int row = m0 + wr * 64 + mi * 16 + lg * 4 + r;
          const int col = n0 + wc * 64 + ni * 16 + ln;
          const float v = (acc[mi][ni][r] + bias[col]) * scale;
          Cp[(size_t)row * 1024 + col] = f2bf(v);
        }
  }
}

// ---------------------------------------------------------------------------
// Causal flash attention v14: single-chain waves, 4096 waves, natural regs
// (VGPR 76, round 15), with BLOCK-UNIFORM q-tile assignment.
// Round-15 lesson: per-BLOCK-constant work is the wrong invariant - a block
// retires on its LONGEST wave, so nt spread {2,17,18,33} inside one block
// idles half the wave-slots (occupancy 15%). Fix: nt(qt)=floor(qt/2)+1 is
// equal for adjacent qt, so block k owns q-tiles {4k..4k+3} with nt spread
// <= 1. Block durations now vary (~2k+2) -> dispatch longest-first
// (k = 15 - id>>6); 1024 blocks on 256 CUs backfill the tail. XCD mapping
// unchanged (bh fixed by id&63 for all 16 blocks of a bh).
// ---------------------------------------------------------------------------
__device__ __forceinline__ void tile_chain(
    const bf16x8* kf0, const bf16x8* kf1,
    const bf16x8* vf0, const bf16x8* vf1,
    const bf16x8* qf, const f32x16& zv,
    f32x16& o0, f32x16& o1, float& m_run, float& l_run,
    const int kv0, const int qw, const int q, const int hi)
{
  f32x16 s0, s1;
  __builtin_amdgcn_s_setprio(1);
  s0 = mfma32(kf0[0], qf[0], zv);
#pragma unroll
  for (int c = 1; c < 4; c++) s0 = mfma32(kf0[c], qf[c], s0);
  s1 = mfma32(kf1[0], qf[0], zv);
#pragma unroll
  for (int c = 1; c < 4; c++) s1 = mfma32(kf1[c], qf[c], s1);
  __builtin_amdgcn_s_setprio(0);

  if (kv0 + 63 > qw) {
    const int qrel = q - kv0 - 4 * hi;
#pragma unroll
    for (int r = 0; r < 16; r++) {
      const int cst = (r & 3) + 8 * (r >> 2);
      if (cst > qrel) s0[r] = -3.0e38f;
      if (cst + 32 > qrel) s1[r] = -3.0e38f;
    }
  }

  float mx;
  {
    float t[8];
#pragma unroll
    for (int i = 0; i < 8; i++)
      t[i] = fmaxf(fmaxf(s0[i], s0[i + 8]), fmaxf(s1[i], s1[i + 8]));
    const float a0 = fmaxf(fmaxf(t[0], t[1]), fmaxf(t[2], t[3]));
    const float a1 = fmaxf(fmaxf(t[4], t[5]), fmaxf(t[6], t[7]));
    mx = fmaxf(a0, a1);
    u32x2 r = plswap(__float_as_uint(mx), __float_as_uint(mx));
    mx = fmaxf(__uint_as_float(r[0]), __uint_as_float(r[1]));
  }
  // T13 defer-max: only rescale when the max grew by > 8 (wave-uniform).
  if (!__all(mx - m_run <= 8.0f)) {
    const float mn = fmaxf(m_run, mx);
    const float rr = exp2f(m_run - mn);
    m_run = mn;
    l_run *= rr;
#pragma unroll
    for (int i = 0; i < 16; i++) { o0[i] *= rr; o1[i] *= rr; }
  }
  const float mn = m_run;
#pragma unroll
  for (int i = 0; i < 16; i++) s0[i] = exp2f(s0[i] - mn);
#pragma unroll
  for (int i = 0; i < 16; i++) s1[i] = exp2f(s1[i] - mn);
  float ts;
  {
    float t[8];
#pragma unroll
    for (int i = 0; i < 8; i++) t[i] = (s0[i] + s0[i + 8]) + (s1[i] + s1[i + 8]);
    ts = ((t[0] + t[1]) + (t[2] + t[3])) + ((t[4] + t[5]) + (t[6] + t[7]));
    u32x2 r = plswap(__float_as_uint(ts), __float_as_uint(ts));
    ts = __uint_as_float(r[0]) + __uint_as_float(r[1]);
  }
  l_run += ts;

  // P -> PV B-fragments: cvt_pk pairs + permlane32 half-exchange.
  PB pb[4];
  {
    unsigned c0 = cvtpk(s0[0], s0[1]),   c1 = cvtpk(s0[2], s0[3]);
    unsigned c2 = cvtpk(s0[4], s0[5]),   c3 = cvtpk(s0[6], s0[7]);
    unsigned c4 = cvtpk(s0[8], s0[9]),   c5 = cvtpk(s0[10], s0[11]);
    unsigned c6 = cvtpk(s0[12], s0[13]), c7 = cvtpk(s0[14], s0[15]);
    u32x2 r02 = plswap(c0, c2), r13 = plswap(c1, c3);
    u32x2 r46 = plswap(c4, c6), r57 = plswap(c5, c7);
    pb[0].u = (u32x4){r02[0], r13[0], r02[1], r13[1]};
    pb[1].u = (u32x4){r46[0], r57[0], r46[1], r57[1]};
  }
  {
    unsigned c0 = cvtpk(s1[0], s1[1]),   c1 = cvtpk(s1[2], s1[3]);
    unsigned c2 = cvtpk(s1[4], s1[5]),   c3 = cvtpk(s1[6], s1[7]);
    unsigned c4 = cvtpk(s1[8], s1[9]),   c5 = cvtpk(s1[10], s1[11]);
    unsigned c6 = cvtpk(s1[12], s1[13]), c7 = cvtpk(s1[14], s1[15]);
    u32x2 r02 = plswap(c0, c2), r13 = plswap(c1, c3);
    u32x2 r46 = plswap(c4, c6), r57 = plswap(c5, c7);
    pb[2].u = (u32x4){r02[0], r13[0], r02[1], r13[1]};
    pb[3].u = (u32x4){r46[0], r57[0], r46[1], r57[1]};
  }

  __builtin_amdgcn_s_setprio(1);
#pragma unroll
  for (int kc = 0; kc < 4; kc++) {
    o0 = mfma32(vf0[kc], pb[kc].b, o0);
    o1 = mfma32(vf1[kc], pb[kc].b, o1);
  }
  __builtin_amdgcn_s_setprio(0);
}

__device__ __forceinline__ void attn_epilogue(
    short* cp, const f32x16& o0, const f32x16& o1, float l_run, int hi)
{
  const float inv = 1.0f / l_run;
#pragma unroll
  for (int g = 0; g < 4; g++) {
    s16x4 w0, w1;
#pragma unroll
    for (int j = 0; j < 4; j++) {
      w0[j] = f2bf(o0[g * 4 + j] * inv);   // dh = g*8 + 4*hi + j
      w1[j] = f2bf(o1[g * 4 + j] * inv);   // dh = 32 + g*8 + 4*hi + j
    }
    *(s16x4*)(cp + g * 8 + 4 * hi) = w0;
    *(s16x4*)(cp + 32 + g * 8 + 4 * hi) = w1;
  }
}

__global__ __launch_bounds__(256, 2) void attn_fwd(
    const short* __restrict__ Q, const short* __restrict__ K,
    const short* __restrict__ Vt, short* __restrict__ ctx)
{
  const int tid = threadIdx.x, lane = tid & 63, wid = tid >> 6;
  const int hi = lane >> 5, lq = lane & 31;
  // XCD swizzle: id&7 = XCD; all 16 blocks of one bh share an XCD's L2.
  const int id = (int)blockIdx.x;
  const int bh = (id & 7) * 8 + ((id >> 3) & 7);
  const int k = 15 - (id >> 6);                 // longest blocks dispatch first
  const int b = bh >> 4, h = bh & 15;

  // block-uniform assignment: waves own q-tiles {4k..4k+3}; nt spread <= 1.
  const int qt = 4 * k + wid;
  const int qw = qt * 32;
  const int q = qw + lq;

  bf16x8 qf[4];
  {
    const short* qp = Q + (size_t)(b * T_SEQ + q) * 1024 + h * 64 + hi * 8;
#pragma unroll
    for (int c = 0; c < 4; c++) qf[c] = *(const bf16x8*)(qp + c * 16);
  }

  f32x16 zv;
#pragma unroll
  for (int i = 0; i < 16; i++) zv[i] = 0.f;

  f32x16 o0 = zv, o1 = zv;
  float m_run = -3.0e38f, l_run = 0.f;

  const int nt = (qw + 95) >> 6;

#pragma unroll 1
  for (int it = 0; it < nt; ++it) {
    const int kv0 = it * 64;
    bf16x8 kf0[4], kf1[4], vf0[4], vf1[4];
    {
      const short* kp = K + (size_t)(b * T_SEQ + kv0 + lq) * 1024 + h * 64 + hi * 8;
      const short* vp = Vt + (size_t)(bh * 64 + lq) * T_SEQ + kv0 + hi * 8;
#pragma unroll
      for (int c = 0; c < 4; c++) {
        kf0[c] = *(const bf16x8*)(kp + c * 16);
        kf1[c] = *(const bf16x8*)(kp + 32 * 1024 + c * 16);
        vf0[c] = *(const bf16x8*)(vp + c * 16);
        vf1[c] = *(const bf16x8*)(vp + 32 * T_SEQ + c * 16);
      }
    }
    tile_chain(kf0, kf1, vf0, vf1, qf, zv, o0, o1, m_run, l_run, kv0, qw, q, hi);
  }

  attn_epilogue(ctx + (size_t)(b * T_SEQ + q) * 1024 + h * 64, o0, o1, l_run, hi);
}

// ---------------------------------------------------------------------------
extern "C" void kernel_launch(void* const* d_in, const int* in_sizes, int n_in,
                              void* d_out, int out_size, void* d_ws, size_t ws_size,
                              hipStream_t stream)
{
  (void)in_sizes; (void)n_in; (void)out_size; (void)ws_size;
  const float* x  = (const float*)d_in[0];
  // d_in[1] = causal mask (triu, k=1) — structure is known, not read
  const float* WQ = (const float*)d_in[2];
  const float* bQ = (const float*)d_in[3];
  const float* WK = (const float*)d_in[4];
  const float* bK = (const float*)d_in[5];
  const float* WV = (const float*)d_in[6];
  const float* bV = (const float*)d_in[7];
  const float* WO = (const float*)d_in[8];
  const float* bO = (const float*)d_in[9];
  float* out = (float*)d_out;

  const size_t MB = 1024ull * 1024ull;
  char* w = (char*)d_ws;
  short* xb = (short*)(w);             // 16MB; reused as ctx after QKV GEMMs
  short* Wt = (short*)(w + 16 * MB);   // 8MB: WQt,WKt,WVt,WOt bf16 (contiguous)
  short* Qb = (short*)(w + 24 * MB);   // 16MB
  short* Kb = (short*)(w + 40 * MB);   // 16MB
  short* Vt = (short*)(w + 72 * MB);   // 16MB (written directly by gemm_qkv)
  short* ctx = xb;

  transpose_w_kernel<<<dim3(32, 32, 4), 256, 0, stream>>>(WQ, WK, WV, WO, Wt);
  cvt_x_kernel<<<dim3(MTOK * D_MODEL / 8 / 256), 256, 0, stream>>>(x, xb);

  const float qscale = 0.125f * 1.4426950408889634f;  // fold 1/sqrt(64) * log2(e)
  gemm_qkv<<<dim3(64, 24), 256, 0, stream>>>(xb, Wt, bQ, bK, bV, Qb, Kb, Vt, qscale);

  attn_fwd<<<dim3(1024), 256, 0, stream>>>(Qb, Kb, Vt, ctx);

  gemm_bt<<<dim3(64, 8), 256, 0, stream>>>(ctx, Wt + 3ull * D_MODEL * D_MODEL, bO, out);
}

// Round 17
// 212.762 us; speedup vs baseline: 1.4194x; 1.1385x over previous
//
#include <hip/hip_runtime.h>
#include <hip/hip_bf16.h>
#include <stdint.h>

#define T_SEQ   2048
#define D_MODEL 1024
#define NHEAD   16
#define DHEAD   64
#define BATCH   4
#define MTOK    (BATCH * T_SEQ)   // 8192

typedef __attribute__((ext_vector_type(4))) float f32x4;
typedef __attribute__((ext_vector_type(16))) float f32x16;
typedef __attribute__((ext_vector_type(8))) short bf16x8;
typedef __attribute__((ext_vector_type(4))) short s16x4;
typedef __attribute__((ext_vector_type(4))) unsigned u32x4;
typedef __attribute__((ext_vector_type(2))) unsigned u32x2;

__device__ __forceinline__ f32x4 mfma16(bf16x8 a, bf16x8 b, f32x4 c) {
  return __builtin_amdgcn_mfma_f32_16x16x32_bf16(a, b, c, 0, 0, 0);
}
__device__ __forceinline__ f32x16 mfma32(bf16x8 a, bf16x8 b, f32x16 c) {
  return __builtin_amdgcn_mfma_f32_32x32x16_bf16(a, b, c, 0, 0, 0);
}

__device__ __forceinline__ short f2bf(float f) {
  __hip_bfloat16 h = __float2bfloat16(f);
  return *reinterpret_cast<short*>(&h);
}

// v_cvt_pk_bf16_f32: dst = {lo16: bf16(a), hi16: bf16(b)} (no builtin on gfx950)
__device__ __forceinline__ unsigned cvtpk(float a, float b) {
  unsigned r;
  asm("v_cvt_pk_bf16_f32 %0, %1, %2" : "=v"(r) : "v"(a), "v"(b));
  return r;
}

// permlane32_swap via the INTRINSIC (T12 recipe): returns the pair
//   r[0] = {a.row0, b.row0},  r[1] = {a.row1, b.row1}.
// Round-11 lesson: the raw "+v","+v" inline-asm form is unsafe when both
// operands carry the same value (LLVM coalesces them into ONE register ->
// v_permlane32_swap_b32 v5,v5 scrambles rows instead of exchanging) -> NaN.
__device__ __forceinline__ u32x2 plswap(unsigned a, unsigned b) {
  return __builtin_amdgcn_permlane32_swap(a, b, false, false);
}

union PB { u32x4 u; bf16x8 b; };

#define GLD_LDS16(gp, lp)                                                      \
  __builtin_amdgcn_global_load_lds(                                            \
      (const __attribute__((address_space(1))) void*)(gp),                     \
      (__attribute__((address_space(3))) void*)(lp), 16, 0, 0)

// ---------------------------------------------------------------------------
// Weight transpose + fp32->bf16 convert: Wt[n][k] = W[k][n], 4 weights
// ---------------------------------------------------------------------------
__global__ __launch_bounds__(256) void transpose_w_kernel(
    const float* __restrict__ W0, const float* __restrict__ W1,
    const float* __restrict__ W2, const float* __restrict__ W3,
    short* __restrict__ out)
{
  const int z = blockIdx.z;
  const float* W = (z == 0) ? W0 : (z == 1) ? W1 : (z == 2) ? W2 : W3;
  short* o = out + (size_t)z * D_MODEL * D_MODEL;
  __shared__ float tile[32][33];
  const int n0 = blockIdx.x * 32, k0 = blockIdx.y * 32;
  const int c = threadIdx.x & 31, r = threadIdx.x >> 5;
#pragma unroll
  for (int i = 0; i < 4; i++)
    tile[r + i * 8][c] = W[(size_t)(k0 + r + i * 8) * D_MODEL + n0 + c];
  __syncthreads();
#pragma unroll
  for (int i = 0; i < 4; i++)
    o[(size_t)(n0 + r + i * 8) * D_MODEL + k0 + c] = f2bf(tile[c][r + i * 8]);
}

// ---------------------------------------------------------------------------
// x fp32 -> bf16 (8 elements / thread)
// ---------------------------------------------------------------------------
__global__ __launch_bounds__(256) void cvt_x_kernel(
    const float* __restrict__ x, short* __restrict__ xb)
{
  const size_t i = (size_t)blockIdx.x * 256 + threadIdx.x;
  const float4 a = ((const float4*)x)[i * 2];
  const float4 b = ((const float4*)x)[i * 2 + 1];
  bf16x8 o;
  o[0] = f2bf(a.x); o[1] = f2bf(a.y); o[2] = f2bf(a.z); o[3] = f2bf(a.w);
  o[4] = f2bf(b.x); o[5] = f2bf(b.y); o[6] = f2bf(b.z); o[7] = f2bf(b.w);
  ((bf16x8*)xb)[i] = o;
}

// ---------------------------------------------------------------------------
// GEMM: C[M][1024] = A[M][1024](bf16) * Bt[1024][1024]^T(bf16, N-major) + bias
// (final WO projection; fp32 out)
// ---------------------------------------------------------------------------
__global__ __launch_bounds__(256) void gemm_bt(
    const short* __restrict__ A, const short* __restrict__ Bt,
    const float* __restrict__ bias, float* __restrict__ Cp)
{
  __shared__ __align__(16) short As[128 * 32];
  __shared__ __align__(16) short Bs[128 * 32];
  const int tid = threadIdx.x, lane = tid & 63, wid = tid >> 6;
  const int wr = wid >> 1, wc = wid & 1;
  const int lg = lane >> 4, ln = lane & 15;
  const int m0 = blockIdx.x * 128, n0 = blockIdx.y * 128;
  const int lrow = lane >> 2, lchunk = lane & 3;

  f32x4 acc[4][4];
#pragma unroll
  for (int i = 0; i < 4; i++)
#pragma unroll
    for (int j = 0; j < 4; j++) acc[i][j] = {0.f, 0.f, 0.f, 0.f};

  for (int k0 = 0; k0 < 1024; k0 += 32) {
#pragma unroll
    for (int s = 0; s < 2; ++s) {
      const int rbase = (wid * 2 + s) * 16;
      const short* gpa = A + (size_t)(m0 + rbase + lrow) * 1024 + k0 + lchunk * 8;
      GLD_LDS16(gpa, As + rbase * 32);
      const short* gpb = Bt + (size_t)(n0 + rbase + lrow) * 1024 + k0 + lchunk * 8;
      GLD_LDS16(gpb, Bs + rbase * 32);
    }
    __syncthreads();
    bf16x8 a[4], b[4];
#pragma unroll
    for (int mi = 0; mi < 4; mi++)
      a[mi] = *(const bf16x8*)(As + (wr * 64 + mi * 16 + ln) * 32 + lg * 8);
#pragma unroll
    for (int ni = 0; ni < 4; ni++)
      b[ni] = *(const bf16x8*)(Bs + (wc * 64 + ni * 16 + ln) * 32 + lg * 8);
#pragma unroll
    for (int mi = 0; mi < 4; mi++)
#pragma unroll
      for (int ni = 0; ni < 4; ni++)
        acc[mi][ni] = mfma16(a[mi], b[ni], acc[mi][ni]);
    __syncthreads();
  }

#pragma unroll
  for (int mi = 0; mi < 4; mi++)
#pragma unroll
    for (int ni = 0; ni < 4; ni++)
#pragma unroll
      for (int r = 0; r < 4; r++) {
        const int row = m0 + wr * 64 + mi * 16 + lg * 4 + r;
        const int col = n0 + wc * 64 + ni * 16 + ln;
        Cp[(size_t)row * 1024 + col] = acc[mi][ni][r] + bias[col];
      }
}

// ---------------------------------------------------------------------------
// Fused QKV GEMM: Wt is the contiguous [3072][1024] concat of WQt/WKt/WVt.
// One dispatch (grid 64x24). Q scaled by 0.125*log2e. V segment written
// directly in Vt[b][h][dh][t] layout (round 13 - deletes transpose_v).
// ---------------------------------------------------------------------------
__global__ __launch_bounds__(256) void gemm_qkv(
    const short* __restrict__ A, const short* __restrict__ Wt,
    const float* __restrict__ bQ, const float* __restrict__ bK,
    const float* __restrict__ bV,
    short* __restrict__ Qb, short* __restrict__ Kb, short* __restrict__ Vt,
    float qscale)
{
  __shared__ __align__(16) short As[128 * 32];
  __shared__ __align__(16) short Bs[128 * 32];
  const int tid = threadIdx.x, lane = tid & 63, wid = tid >> 6;
  const int wr = wid >> 1, wc = wid & 1;
  const int lg = lane >> 4, ln = lane & 15;
  const int m0 = blockIdx.x * 128;
  const int nglob = blockIdx.y * 128;          // 0..3071
  const int seg = blockIdx.y >> 3;             // 0=Q 1=K 2=V
  const int n0 = nglob & 1023;
  const short* Bt = Wt + (size_t)nglob * 1024; // concat rows are n-major
  const float* bias = (seg == 0) ? bQ : (seg == 1) ? bK : bV;
  const float scale = (seg == 0) ? qscale : 1.0f;
  const int lrow = lane >> 2, lchunk = lane & 3;

  f32x4 acc[4][4];
#pragma unroll
  for (int i = 0; i < 4; i++)
#pragma unroll
    for (int j = 0; j < 4; j++) acc[i][j] = {0.f, 0.f, 0.f, 0.f};

  for (int k0 = 0; k0 < 1024; k0 += 32) {
#pragma unroll
    for (int s = 0; s < 2; ++s) {
      const int rbase = (wid * 2 + s) * 16;
      const short* gpa = A + (size_t)(m0 + rbase + lrow) * 1024 + k0 + lchunk * 8;
      GLD_LDS16(gpa, As + rbase * 32);
      const short* gpb = Bt + (size_t)(rbase + lrow) * 1024 + k0 + lchunk * 8;
      GLD_LDS16(gpb, Bs + rbase * 32);
    }
    __syncthreads();
    bf16x8 a[4], b[4];
#pragma unroll
    for (int mi = 0; mi < 4; mi++)
      a[mi] = *(const bf16x8*)(As + (wr * 64 + mi * 16 + ln) * 32 + lg * 8);
#pragma unroll
    for (int ni = 0; ni < 4; ni++)
      b[ni] = *(const bf16x8*)(Bs + (wc * 64 + ni * 16 + ln) * 32 + lg * 8);
#pragma unroll
    for (int mi = 0; mi < 4; mi++)
#pragma unroll
      for (int ni = 0; ni < 4; ni++)
        acc[mi][ni] = mfma16(a[mi], b[ni], acc[mi][ni]);
    __syncthreads();
  }

  if (seg == 2) {
    // direct Vt[b][h][dh][t] write: 8B per (mi,ni)
    const int bb = m0 >> 11;                   // batch, constant per block
    const int tbase = (m0 & 2047) + wr * 64 + lg * 4;
#pragma unroll
    for (int mi = 0; mi < 4; mi++)
#pragma unroll
      for (int ni = 0; ni < 4; ni++) {
        const int col = n0 + wc * 64 + ni * 16 + ln;
        const int hh = col >> 6, dh = col & 63;
        s16x4 w;
#pragma unroll
        for (int r = 0; r < 4; r++) w[r] = f2bf(acc[mi][ni][r] + bias[col]);
        *(s16x4*)(Vt + (size_t)((bb * 16 + hh) * 64 + dh) * T_SEQ +
                  tbase + mi * 16) = w;
      }
  } else {
    short* Cp = (seg == 0) ? Qb : Kb;
#pragma unroll
    for (int mi = 0; mi < 4; mi++)
#pragma unroll
      for (int ni = 0; ni < 4; ni++)
#pragma unroll
        for (int r = 0; r < 4; r++) {
          const int row = m0 + wr * 64 + mi * 16 + lg * 4 + r;
          const int col = n0 + wc * 64 + ni * 16 + ln;
          const float v = (acc[mi][ni][r] + bias[col]) * scale;
          Cp[(size_t)row * 1024 + col] = f2bf(v);
        }
  }
}

// ---------------------------------------------------------------------------
// Causal flash attention (round-13 configuration, session optimum):
// dual-q-chain waves (32 q-rows/chain, pair (p,63-p), shared K/V loads),
// 2 waves/SIMD, permlane32_swap cross-lane ops, T13 defer-max,
// persistent-zero MFMA C-in, XCD swizzle. Verified 119.4us / VGPR 120.
// Rounds 7,9,14-16 falsified all wider-TLP variants: split-KV spills,
// split-Q doubles loads, single-chain loses shared-load ILP (151us best).
// ---------------------------------------------------------------------------
__device__ __forceinline__ void tile_chain(
    const bf16x8* kf0, const bf16x8* kf1,
    const bf16x8* vf0, const bf16x8* vf1,
    const bf16x8* qf, const f32x16& zv,
    f32x16& o0, f32x16& o1, float& m_run, float& l_run,
    const int kv0, const int qw, const int q, const int hi)
{
  f32x16 s0, s1;
  __builtin_amdgcn_s_setprio(1);
  s0 = mfma32(kf0[0], qf[0], zv);
#pragma unroll
  for (int c = 1; c < 4; c++) s0 = mfma32(kf0[c], qf[c], s0);
  s1 = mfma32(kf1[0], qf[0], zv);
#pragma unroll
  for (int c = 1; c < 4; c++) s1 = mfma32(kf1[c], qf[c], s1);
  __builtin_amdgcn_s_setprio(0);

  if (kv0 + 63 > qw) {
    const int qrel = q - kv0 - 4 * hi;
#pragma unroll
    for (int r = 0; r < 16; r++) {
      const int cst = (r & 3) + 8 * (r >> 2);
      if (cst > qrel) s0[r] = -3.0e38f;
      if (cst + 32 > qrel) s1[r] = -3.0e38f;
    }
  }

  float mx;
  {
    float t[8];
#pragma unroll
    for (int i = 0; i < 8; i++)
      t[i] = fmaxf(fmaxf(s0[i], s0[i + 8]), fmaxf(s1[i], s1[i + 8]));
    const float a0 = fmaxf(fmaxf(t[0], t[1]), fmaxf(t[2], t[3]));
    const float a1 = fmaxf(fmaxf(t[4], t[5]), fmaxf(t[6], t[7]));
    mx = fmaxf(a0, a1);
    u32x2 r = plswap(__float_as_uint(mx), __float_as_uint(mx));
    mx = fmaxf(__uint_as_float(r[0]), __uint_as_float(r[1]));
  }
  // T13 defer-max: only rescale when the max grew by > 8 (wave-uniform).
  if (!__all(mx - m_run <= 8.0f)) {
    const float mn = fmaxf(m_run, mx);
    const float rr = exp2f(m_run - mn);
    m_run = mn;
    l_run *= rr;
#pragma unroll
    for (int i = 0; i < 16; i++) { o0[i] *= rr; o1[i] *= rr; }
  }
  const float mn = m_run;
#pragma unroll
  for (int i = 0; i < 16; i++) s0[i] = exp2f(s0[i] - mn);
#pragma unroll
  for (int i = 0; i < 16; i++) s1[i] = exp2f(s1[i] - mn);
  float ts;
  {
    float t[8];
#pragma unroll
    for (int i = 0; i < 8; i++) t[i] = (s0[i] + s0[i + 8]) + (s1[i] + s1[i + 8]);
    ts = ((t[0] + t[1]) + (t[2] + t[3])) + ((t[4] + t[5]) + (t[6] + t[7]));
    u32x2 r = plswap(__float_as_uint(ts), __float_as_uint(ts));
    ts = __uint_as_float(r[0]) + __uint_as_float(r[1]);
  }
  l_run += ts;

  // P -> PV B-fragments: cvt_pk pairs + permlane32 half-exchange.
  PB pb[4];
  {
    unsigned c0 = cvtpk(s0[0], s0[1]),   c1 = cvtpk(s0[2], s0[3]);
    unsigned c2 = cvtpk(s0[4], s0[5]),   c3 = cvtpk(s0[6], s0[7]);
    unsigned c4 = cvtpk(s0[8], s0[9]),   c5 = cvtpk(s0[10], s0[11]);
    unsigned c6 = cvtpk(s0[12], s0[13]), c7 = cvtpk(s0[14], s0[15]);
    u32x2 r02 = plswap(c0, c2), r13 = plswap(c1, c3);
    u32x2 r46 = plswap(c4, c6), r57 = plswap(c5, c7);
    pb[0].u = (u32x4){r02[0], r13[0], r02[1], r13[1]};
    pb[1].u = (u32x4){r46[0], r57[0], r46[1], r57[1]};
  }
  {
    unsigned c0 = cvtpk(s1[0], s1[1]),   c1 = cvtpk(s1[2], s1[3]);
    unsigned c2 = cvtpk(s1[4], s1[5]),   c3 = cvtpk(s1[6], s1[7]);
    unsigned c4 = cvtpk(s1[8], s1[9]),   c5 = cvtpk(s1[10], s1[11]);
    unsigned c6 = cvtpk(s1[12], s1[13]), c7 = cvtpk(s1[14], s1[15]);
    u32x2 r02 = plswap(c0, c2), r13 = plswap(c1, c3);
    u32x2 r46 = plswap(c4, c6), r57 = plswap(c5, c7);
    pb[2].u = (u32x4){r02[0], r13[0], r02[1], r13[1]};
    pb[3].u = (u32x4){r46[0], r57[0], r46[1], r57[1]};
  }

  __builtin_amdgcn_s_setprio(1);
#pragma unroll
  for (int kc = 0; kc < 4; kc++) {
    o0 = mfma32(vf0[kc], pb[kc].b, o0);
    o1 = mfma32(vf1[kc], pb[kc].b, o1);
  }
  __builtin_amdgcn_s_setprio(0);
}

__device__ __forceinline__ void attn_epilogue(
    short* cp, const f32x16& o0, const f32x16& o1, float l_run, int hi)
{
  const float inv = 1.0f / l_run;
#pragma unroll
  for (int g = 0; g < 4; g++) {
    s16x4 w0, w1;
#pragma unroll
    for (int j = 0; j < 4; j++) {
      w0[j] = f2bf(o0[g * 4 + j] * inv);   // dh = g*8 + 4*hi + j
      w1[j] = f2bf(o1[g * 4 + j] * inv);   // dh = 32 + g*8 + 4*hi + j
    }
    *(s16x4*)(cp + g * 8 + 4 * hi) = w0;
    *(s16x4*)(cp + 32 + g * 8 + 4 * hi) = w1;
  }
}

__global__ __launch_bounds__(256, 2) void attn_fwd(
    const short* __restrict__ Q, const short* __restrict__ K,
    const short* __restrict__ Vt, short* __restrict__ ctx)
{
  const int tid = threadIdx.x, lane = tid & 63, wid = tid >> 6;
  const int hi = lane >> 5, lq = lane & 31;
  // XCD swizzle: 512 blocks, id%8 = XCD (round-robin). All 8 blocks of one
  // bh land on one XCD: bh = (id&7)*8 + ((id>>3)&7); pair-group = id>>6.
  const int id = (int)blockIdx.x;
  const int bh = (id & 7) * 8 + ((id >> 3) & 7);
  const int p = (id >> 6) * 4 + wid;            // pair index 0..31
  const int b = bh >> 4, h = bh & 15;

  const int qtA = p, qtB = 63 - p;
  const int qwA = qtA * 32, qwB = qtB * 32;
  const int qA = qwA + lq, qB = qwB + lq;

  bf16x8 qfA[4], qfB[4];
  {
    const short* qpA = Q + (size_t)(b * T_SEQ + qA) * 1024 + h * 64 + hi * 8;
    const short* qpB = Q + (size_t)(b * T_SEQ + qB) * 1024 + h * 64 + hi * 8;
#pragma unroll
    for (int c = 0; c < 4; c++) {
      qfA[c] = *(const bf16x8*)(qpA + c * 16);
      qfB[c] = *(const bf16x8*)(qpB + c * 16);
    }
  }

  f32x16 zv;
#pragma unroll
  for (int i = 0; i < 16; i++) zv[i] = 0.f;

  f32x16 oA0 = zv, oA1 = zv, oB0 = zv, oB1 = zv;
  float mA = -3.0e38f, lA = 0.f, mB = -3.0e38f, lB = 0.f;

  const int ntA = (qwA + 95) >> 6, ntB = (qwB + 95) >> 6;

#pragma unroll 1
  for (int it = 0; it < ntB; ++it) {
    const int kv0 = it * 64;
    bf16x8 kf0[4], kf1[4], vf0[4], vf1[4];
    {
      const short* kp = K + (size_t)(b * T_SEQ + kv0 + lq) * 1024 + h * 64 + hi * 8;
      const short* vp = Vt + (size_t)(bh * 64 + lq) * T_SEQ + kv0 + hi * 8;
#pragma unroll
      for (int c = 0; c < 4; c++) {
        kf0[c] = *(const bf16x8*)(kp + c * 16);
        kf1[c] = *(const bf16x8*)(kp + 32 * 1024 + c * 16);
        vf0[c] = *(const bf16x8*)(vp + c * 16);
        vf1[c] = *(const bf16x8*)(vp + 32 * T_SEQ + c * 16);
      }
    }
    tile_chain(kf0, kf1, vf0, vf1, qfB, zv, oB0, oB1, mB, lB, kv0, qwB, qB, hi);
    if (it < ntA)
      tile_chain(kf0, kf1, vf0, vf1, qfA, zv, oA0, oA1, mA, lA, kv0, qwA, qA, hi);
  }

  attn_epilogue(ctx + (size_t)(b * T_SEQ + qA) * 1024 + h * 64, oA0, oA1, lA, hi);
  attn_epilogue(ctx + (size_t)(b * T_SEQ + qB) * 1024 + h * 64, oB0, oB1, lB, hi);
}

// ---------------------------------------------------------------------------
extern "C" void kernel_launch(void* const* d_in, const int* in_sizes, int n_in,
                              void* d_out, int out_size, void* d_ws, size_t ws_size,
                              hipStream_t stream)
{
  (void)in_sizes; (void)n_in; (void)out_size; (void)ws_size;
  const float* x  = (const float*)d_in[0];
  // d_in[1] = causal mask (triu, k=1) — structure is known, not read
  const float* WQ = (const float*)d_in[2];
  const float* bQ = (const float*)d_in[3];
  const float* WK = (const float*)d_in[4];
  const float* bK = (const float*)d_in[5];
  const float* WV = (const float*)d_in[6];
  const float* bV = (const float*)d_in[7];
  const float* WO = (const float*)d_in[8];
  const float* bO = (const float*)d_in[9];
  float* out = (float*)d_out;

  const size_t MB = 1024ull * 1024ull;
  char* w = (char*)d_ws;
  short* xb = (short*)(w);             // 16MB; reused as ctx after QKV GEMMs
  short* Wt = (short*)(w + 16 * MB);   // 8MB: WQt,WKt,WVt,WOt bf16 (contiguous)
  short* Qb = (short*)(w + 24 * MB);   // 16MB
  short* Kb = (short*)(w + 40 * MB);   // 16MB
  short* Vt = (short*)(w + 72 * MB);   // 16MB (written directly by gemm_qkv)
  short* ctx = xb;

  transpose_w_kernel<<<dim3(32, 32, 4), 256, 0, stream>>>(WQ, WK, WV, WO, Wt);
  cvt_x_kernel<<<dim3(MTOK * D_MODEL / 8 / 256), 256, 0, stream>>>(x, xb);

  const float qscale = 0.125f * 1.4426950408889634f;  // fold 1/sqrt(64) * log2(e)
  gemm_qkv<<<dim3(64, 24), 256, 0, stream>>>(xb, Wt, bQ, bK, bV, Qb, Kb, Vt, qscale);

  attn_fwd<<<dim3(512), 256, 0, stream>>>(Qb, Kb, Vt, ctx);

  gemm_bt<<<dim3(64, 8), 256, 0, stream>>>(ctx, Wt + 3ull * D_MODEL * D_MODEL, bO, out);
}

// Round 18
// 209.631 us; speedup vs baseline: 1.4406x; 1.0149x over previous
//
#include <hip/hip_runtime.h>
#include <hip/hip_bf16.h>
#include <stdint.h>

#define T_SEQ   2048
#define D_MODEL 1024
#define NHEAD   16
#define DHEAD   64
#define BATCH   4
#define MTOK    (BATCH * T_SEQ)   // 8192

typedef __attribute__((ext_vector_type(4))) float f32x4;
typedef __attribute__((ext_vector_type(16))) float f32x16;
typedef __attribute__((ext_vector_type(8))) short bf16x8;
typedef __attribute__((ext_vector_type(4))) short s16x4;
typedef __attribute__((ext_vector_type(4))) unsigned u32x4;
typedef __attribute__((ext_vector_type(2))) unsigned u32x2;

__device__ __forceinline__ f32x4 mfma16(bf16x8 a, bf16x8 b, f32x4 c) {
  return __builtin_amdgcn_mfma_f32_16x16x32_bf16(a, b, c, 0, 0, 0);
}
__device__ __forceinline__ f32x16 mfma32(bf16x8 a, bf16x8 b, f32x16 c) {
  return __builtin_amdgcn_mfma_f32_32x32x16_bf16(a, b, c, 0, 0, 0);
}

__device__ __forceinline__ short f2bf(float f) {
  __hip_bfloat16 h = __float2bfloat16(f);
  return *reinterpret_cast<short*>(&h);
}

// v_cvt_pk_bf16_f32: dst = {lo16: bf16(a), hi16: bf16(b)} (no builtin on gfx950)
__device__ __forceinline__ unsigned cvtpk(float a, float b) {
  unsigned r;
  asm("v_cvt_pk_bf16_f32 %0, %1, %2" : "=v"(r) : "v"(a), "v"(b));
  return r;
}

// permlane32_swap via the INTRINSIC (T12 recipe): returns the pair
//   r[0] = {a.row0, b.row0},  r[1] = {a.row1, b.row1}.
// Round-11 lesson: the raw "+v","+v" inline-asm form is unsafe when both
// operands carry the same value (LLVM coalesces them into ONE register ->
// v_permlane32_swap_b32 v5,v5 scrambles rows instead of exchanging) -> NaN.
__device__ __forceinline__ u32x2 plswap(unsigned a, unsigned b) {
  return __builtin_amdgcn_permlane32_swap(a, b, false, false);
}

union PB { u32x4 u; bf16x8 b; };

#define GLD_LDS16(gp, lp)                                                      \
  __builtin_amdgcn_global_load_lds(                                            \
      (const __attribute__((address_space(1))) void*)(gp),                     \
      (__attribute__((address_space(3))) void*)(lp), 16, 0, 0)

// ---------------------------------------------------------------------------
// Fused prep: z<4 -> weight transpose+convert Wt[n][k]=bf16(W[k][n]);
// z>=4 -> x fp32->bf16 (chunk = bx + by*32 + (z-4)*1024, 2048 elems/block).
// One dispatch instead of two (saves a launch slot + gap; bodies unchanged).
// ---------------------------------------------------------------------------
__global__ __launch_bounds__(256) void prep_kernel(
    const float* __restrict__ W0, const float* __restrict__ W1,
    const float* __restrict__ W2, const float* __restrict__ W3,
    short* __restrict__ Wt,
    const float* __restrict__ x, short* __restrict__ xb)
{
  const int z = blockIdx.z;
  if (z < 4) {
    const float* W = (z == 0) ? W0 : (z == 1) ? W1 : (z == 2) ? W2 : W3;
    short* o = Wt + (size_t)z * D_MODEL * D_MODEL;
    __shared__ float tile[32][33];
    const int n0 = blockIdx.x * 32, k0 = blockIdx.y * 32;
    const int c = threadIdx.x & 31, r = threadIdx.x >> 5;
#pragma unroll
    for (int i = 0; i < 4; i++)
      tile[r + i * 8][c] = W[(size_t)(k0 + r + i * 8) * D_MODEL + n0 + c];
    __syncthreads();
#pragma unroll
    for (int i = 0; i < 4; i++)
      o[(size_t)(n0 + r + i * 8) * D_MODEL + k0 + c] = f2bf(tile[c][r + i * 8]);
  } else {
    const int chunk = (int)blockIdx.x + (int)blockIdx.y * 32 + (z - 4) * 1024;
    const size_t i = (size_t)chunk * 256 + threadIdx.x;
    const float4 a = ((const float4*)x)[i * 2];
    const float4 b = ((const float4*)x)[i * 2 + 1];
    bf16x8 o;
    o[0] = f2bf(a.x); o[1] = f2bf(a.y); o[2] = f2bf(a.z); o[3] = f2bf(a.w);
    o[4] = f2bf(b.x); o[5] = f2bf(b.y); o[6] = f2bf(b.z); o[7] = f2bf(b.w);
    ((bf16x8*)xb)[i] = o;
  }
}

// ---------------------------------------------------------------------------
// GEMM: C[M][1024] = A[M][1024](bf16) * Bt[1024][1024]^T(bf16, N-major) + bias
// (final WO projection; fp32 out)
// ---------------------------------------------------------------------------
__global__ __launch_bounds__(256) void gemm_bt(
    const short* __restrict__ A, const short* __restrict__ Bt,
    const float* __restrict__ bias, float* __restrict__ Cp)
{
  __shared__ __align__(16) short As[128 * 32];
  __shared__ __align__(16) short Bs[128 * 32];
  const int tid = threadIdx.x, lane = tid & 63, wid = tid >> 6;
  const int wr = wid >> 1, wc = wid & 1;
  const int lg = lane >> 4, ln = lane & 15;
  const int m0 = blockIdx.x * 128, n0 = blockIdx.y * 128;
  const int lrow = lane >> 2, lchunk = lane & 3;

  f32x4 acc[4][4];
#pragma unroll
  for (int i = 0; i < 4; i++)
#pragma unroll
    for (int j = 0; j < 4; j++) acc[i][j] = {0.f, 0.f, 0.f, 0.f};

  for (int k0 = 0; k0 < 1024; k0 += 32) {
#pragma unroll
    for (int s = 0; s < 2; ++s) {
      const int rbase = (wid * 2 + s) * 16;
      const short* gpa = A + (size_t)(m0 + rbase + lrow) * 1024 + k0 + lchunk * 8;
      GLD_LDS16(gpa, As + rbase * 32);
      const short* gpb = Bt + (size_t)(n0 + rbase + lrow) * 1024 + k0 + lchunk * 8;
      GLD_LDS16(gpb, Bs + rbase * 32);
    }
    __syncthreads();
    bf16x8 a[4], b[4];
#pragma unroll
    for (int mi = 0; mi < 4; mi++)
      a[mi] = *(const bf16x8*)(As + (wr * 64 + mi * 16 + ln) * 32 + lg * 8);
#pragma unroll
    for (int ni = 0; ni < 4; ni++)
      b[ni] = *(const bf16x8*)(Bs + (wc * 64 + ni * 16 + ln) * 32 + lg * 8);
#pragma unroll
    for (int mi = 0; mi < 4; mi++)
#pragma unroll
      for (int ni = 0; ni < 4; ni++)
        acc[mi][ni] = mfma16(a[mi], b[ni], acc[mi][ni]);
    __syncthreads();
  }

#pragma unroll
  for (int mi = 0; mi < 4; mi++)
#pragma unroll
    for (int ni = 0; ni < 4; ni++)
#pragma unroll
      for (int r = 0; r < 4; r++) {
        const int row = m0 + wr * 64 + mi * 16 + lg * 4 + r;
        const int col = n0 + wc * 64 + ni * 16 + ln;
        Cp[(size_t)row * 1024 + col] = acc[mi][ni][r] + bias[col];
      }
}

// ---------------------------------------------------------------------------
// Fused QKV GEMM: Wt is the contiguous [3072][1024] concat of WQt/WKt/WVt.
// One dispatch (grid 64x24). Q scaled by 0.125*log2e. V segment written
// directly in Vt[b][h][dh][t] layout (round 13 - deletes transpose_v).
// ---------------------------------------------------------------------------
__global__ __launch_bounds__(256) void gemm_qkv(
    const short* __restrict__ A, const short* __restrict__ Wt,
    const float* __restrict__ bQ, const float* __restrict__ bK,
    const float* __restrict__ bV,
    short* __restrict__ Qb, short* __restrict__ Kb, short* __restrict__ Vt,
    float qscale)
{
  __shared__ __align__(16) short As[128 * 32];
  __shared__ __align__(16) short Bs[128 * 32];
  const int tid = threadIdx.x, lane = tid & 63, wid = tid >> 6;
  const int wr = wid >> 1, wc = wid & 1;
  const int lg = lane >> 4, ln = lane & 15;
  const int m0 = blockIdx.x * 128;
  const int nglob = blockIdx.y * 128;          // 0..3071
  const int seg = blockIdx.y >> 3;             // 0=Q 1=K 2=V
  const int n0 = nglob & 1023;
  const short* Bt = Wt + (size_t)nglob * 1024; // concat rows are n-major
  const float* bias = (seg == 0) ? bQ : (seg == 1) ? bK : bV;
  const float scale = (seg == 0) ? qscale : 1.0f;
  const int lrow = lane >> 2, lchunk = lane & 3;

  f32x4 acc[4][4];
#pragma unroll
  for (int i = 0; i < 4; i++)
#pragma unroll
    for (int j = 0; j < 4; j++) acc[i][j] = {0.f, 0.f, 0.f, 0.f};

  for (int k0 = 0; k0 < 1024; k0 += 32) {
#pragma unroll
    for (int s = 0; s < 2; ++s) {
      const int rbase = (wid * 2 + s) * 16;
      const short* gpa = A + (size_t)(m0 + rbase + lrow) * 1024 + k0 + lchunk * 8;
      GLD_LDS16(gpa, As + rbase * 32);
      const short* gpb = Bt + (size_t)(rbase + lrow) * 1024 + k0 + lchunk * 8;
      GLD_LDS16(gpb, Bs + rbase * 32);
    }
    __syncthreads();
    bf16x8 a[4], b[4];
#pragma unroll
    for (int mi = 0; mi < 4; mi++)
      a[mi] = *(const bf16x8*)(As + (wr * 64 + mi * 16 + ln) * 32 + lg * 8);
#pragma unroll
    for (int ni = 0; ni < 4; ni++)
      b[ni] = *(const bf16x8*)(Bs + (wc * 64 + ni * 16 + ln) * 32 + lg * 8);
#pragma unroll
    for (int mi = 0; mi < 4; mi++)
#pragma unroll
      for (int ni = 0; ni < 4; ni++)
        acc[mi][ni] = mfma16(a[mi], b[ni], acc[mi][ni]);
    __syncthreads();
  }

  if (seg == 2) {
    // direct Vt[b][h][dh][t] write: 8B per (mi,ni)
    const int bb = m0 >> 11;                   // batch, constant per block
    const int tbase = (m0 & 2047) + wr * 64 + lg * 4;
#pragma unroll
    for (int mi = 0; mi < 4; mi++)
#pragma unroll
      for (int ni = 0; ni < 4; ni++) {
        const int col = n0 + wc * 64 + ni * 16 + ln;
        const int hh = col >> 6, dh = col & 63;
        s16x4 w;
#pragma unroll
        for (int r = 0; r < 4; r++) w[r] = f2bf(acc[mi][ni][r] + bias[col]);
        *(s16x4*)(Vt + (size_t)((bb * 16 + hh) * 64 + dh) * T_SEQ +
                  tbase + mi * 16) = w;
      }
  } else {
    short* Cp = (seg == 0) ? Qb : Kb;
#pragma unroll
    for (int mi = 0; mi < 4; mi++)
#pragma unroll
      for (int ni = 0; ni < 4; ni++)
#pragma unroll
        for (int r = 0; r < 4; r++) {
          const int row = m0 + wr * 64 + mi * 16 + lg * 4 + r;
          const int col = n0 + wc * 64 + ni * 16 + ln;
          const float v = (acc[mi][ni][r] + bias[col]) * scale;
          Cp[(size_t)row * 1024 + col] = f2bf(v);
        }
  }
}

// ---------------------------------------------------------------------------
// Causal flash attention (round-13 configuration, session optimum):
// dual-q-chain waves (32 q-rows/chain, pair (p,63-p), shared K/V loads),
// 2 waves/SIMD, permlane32_swap cross-lane ops, T13 defer-max,
// persistent-zero MFMA C-in, XCD swizzle. Verified 119.4us / VGPR 120.
// Rounds 7,9,14-16 falsified all wider-TLP variants: split-KV spills,
// split-Q doubles loads, single-chain loses shared-load ILP (151us best).
// ---------------------------------------------------------------------------
__device__ __forceinline__ void tile_chain(
    const bf16x8* kf0, const bf16x8* kf1,
    const bf16x8* vf0, const bf16x8* vf1,
    const bf16x8* qf, const f32x16& zv,
    f32x16& o0, f32x16& o1, float& m_run, float& l_run,
    const int kv0, const int qw, const int q, const int hi)
{
  f32x16 s0, s1;
  __builtin_amdgcn_s_setprio(1);
  s0 = mfma32(kf0[0], qf[0], zv);
#pragma unroll
  for (int c = 1; c < 4; c++) s0 = mfma32(kf0[c], qf[c], s0);
  s1 = mfma32(kf1[0], qf[0], zv);
#pragma unroll
  for (int c = 1; c < 4; c++) s1 = mfma32(kf1[c], qf[c], s1);
  __builtin_amdgcn_s_setprio(0);

  if (kv0 + 63 > qw) {
    const int qrel = q - kv0 - 4 * hi;
#pragma unroll
    for (int r = 0; r < 16; r++) {
      const int cst = (r & 3) + 8 * (r >> 2);
      if (cst > qrel) s0[r] = -3.0e38f;
      if (cst + 32 > qrel) s1[r] = -3.0e38f;
    }
  }

  float mx;
  {
    float t[8];
#pragma unroll
    for (int i = 0; i < 8; i++)
      t[i] = fmaxf(fmaxf(s0[i], s0[i + 8]), fmaxf(s1[i], s1[i + 8]));
    const float a0 = fmaxf(fmaxf(t[0], t[1]), fmaxf(t[2], t[3]));
    const float a1 = fmaxf(fmaxf(t[4], t[5]), fmaxf(t[6], t[7]));
    mx = fmaxf(a0, a1);
    u32x2 r = plswap(__float_as_uint(mx), __float_as_uint(mx));
    mx = fmaxf(__uint_as_float(r[0]), __uint_as_float(r[1]));
  }
  // T13 defer-max: only rescale when the max grew by > 8 (wave-uniform).
  if (!__all(mx - m_run <= 8.0f)) {
    const float mn = fmaxf(m_run, mx);
    const float rr = exp2f(m_run - mn);
    m_run = mn;
    l_run *= rr;
#pragma unroll
    for (int i = 0; i < 16; i++) { o0[i] *= rr; o1[i] *= rr; }
  }
  const float mn = m_run;
#pragma unroll
  for (int i = 0; i < 16; i++) s0[i] = exp2f(s0[i] - mn);
#pragma unroll
  for (int i = 0; i < 16; i++) s1[i] = exp2f(s1[i] - mn);
  float ts;
  {
    float t[8];
#pragma unroll
    for (int i = 0; i < 8; i++) t[i] = (s0[i] + s0[i + 8]) + (s1[i] + s1[i + 8]);
    ts = ((t[0] + t[1]) + (t[2] + t[3])) + ((t[4] + t[5]) + (t[6] + t[7]));
    u32x2 r = plswap(__float_as_uint(ts), __float_as_uint(ts));
    ts = __uint_as_float(r[0]) + __uint_as_float(r[1]);
  }
  l_run += ts;

  // P -> PV B-fragments: cvt_pk pairs + permlane32 half-exchange.
  PB pb[4];
  {
    unsigned c0 = cvtpk(s0[0], s0[1]),   c1 = cvtpk(s0[2], s0[3]);
    unsigned c2 = cvtpk(s0[4], s0[5]),   c3 = cvtpk(s0[6], s0[7]);
    unsigned c4 = cvtpk(s0[8], s0[9]),   c5 = cvtpk(s0[10], s0[11]);
    unsigned c6 = cvtpk(s0[12], s0[13]), c7 = cvtpk(s0[14], s0[15]);
    u32x2 r02 = plswap(c0, c2), r13 = plswap(c1, c3);
    u32x2 r46 = plswap(c4, c6), r57 = plswap(c5, c7);
    pb[0].u = (u32x4){r02[0], r13[0], r02[1], r13[1]};
    pb[1].u = (u32x4){r46[0], r57[0], r46[1], r57[1]};
  }
  {
    unsigned c0 = cvtpk(s1[0], s1[1]),   c1 = cvtpk(s1[2], s1[3]);
    unsigned c2 = cvtpk(s1[4], s1[5]),   c3 = cvtpk(s1[6], s1[7]);
    unsigned c4 = cvtpk(s1[8], s1[9]),   c5 = cvtpk(s1[10], s1[11]);
    unsigned c6 = cvtpk(s1[12], s1[13]), c7 = cvtpk(s1[14], s1[15]);
    u32x2 r02 = plswap(c0, c2), r13 = plswap(c1, c3);
    u32x2 r46 = plswap(c4, c6), r57 = plswap(c5, c7);
    pb[2].u = (u32x4){r02[0], r13[0], r02[1], r13[1]};
    pb[3].u = (u32x4){r46[0], r57[0], r46[1], r57[1]};
  }

  __builtin_amdgcn_s_setprio(1);
#pragma unroll
  for (int kc = 0; kc < 4; kc++) {
    o0 = mfma32(vf0[kc], pb[kc].b, o0);
    o1 = mfma32(vf1[kc], pb[kc].b, o1);
  }
  __builtin_amdgcn_s_setprio(0);
}

__device__ __forceinline__ void attn_epilogue(
    short* cp, const f32x16& o0, const f32x16& o1, float l_run, int hi)
{
  const float inv = 1.0f / l_run;
#pragma unroll
  for (int g = 0; g < 4; g++) {
    s16x4 w0, w1;
#pragma unroll
    for (int j = 0; j < 4; j++) {
      w0[j] = f2bf(o0[g * 4 + j] * inv);   // dh = g*8 + 4*hi + j
      w1[j] = f2bf(o1[g * 4 + j] * inv);   // dh = 32 + g*8 + 4*hi + j
    }
    *(s16x4*)(cp + g * 8 + 4 * hi) = w0;
    *(s16x4*)(cp + 32 + g * 8 + 4 * hi) = w1;
  }
}

__global__ __launch_bounds__(256, 2) void attn_fwd(
    const short* __restrict__ Q, const short* __restrict__ K,
    const short* __restrict__ Vt, short* __restrict__ ctx)
{
  const int tid = threadIdx.x, lane = tid & 63, wid = tid >> 6;
  const int hi = lane >> 5, lq = lane & 31;
  // XCD swizzle: 512 blocks, id%8 = XCD (round-robin). All 8 blocks of one
  // bh land on one XCD: bh = (id&7)*8 + ((id>>3)&7); pair-group = id>>6.
  const int id = (int)blockIdx.x;
  const int bh = (id & 7) * 8 + ((id >> 3) & 7);
  const int p = (id >> 6) * 4 + wid;            // pair index 0..31
  const int b = bh >> 4, h = bh & 15;

  const int qtA = p, qtB = 63 - p;
  const int qwA = qtA * 32, qwB = qtB * 32;
  const int qA = qwA + lq, qB = qwB + lq;

  bf16x8 qfA[4], qfB[4];
  {
    const short* qpA = Q + (size_t)(b * T_SEQ + qA) * 1024 + h * 64 + hi * 8;
    const short* qpB = Q + (size_t)(b * T_SEQ + qB) * 1024 + h * 64 + hi * 8;
#pragma unroll
    for (int c = 0; c < 4; c++) {
      qfA[c] = *(const bf16x8*)(qpA + c * 16);
      qfB[c] = *(const bf16x8*)(qpB + c * 16);
    }
  }

  f32x16 zv;
#pragma unroll
  for (int i = 0; i < 16; i++) zv[i] = 0.f;

  f32x16 oA0 = zv, oA1 = zv, oB0 = zv, oB1 = zv;
  float mA = -3.0e38f, lA = 0.f, mB = -3.0e38f, lB = 0.f;

  const int ntA = (qwA + 95) >> 6, ntB = (qwB + 95) >> 6;

#pragma unroll 1
  for (int it = 0; it < ntB; ++it) {
    const int kv0 = it * 64;
    bf16x8 kf0[4], kf1[4], vf0[4], vf1[4];
    {
      const short* kp = K + (size_t)(b * T_SEQ + kv0 + lq) * 1024 + h * 64 + hi * 8;
      const short* vp = Vt + (size_t)(bh * 64 + lq) * T_SEQ + kv0 + hi * 8;
#pragma unroll
      for (int c = 0; c < 4; c++) {
        kf0[c] = *(const bf16x8*)(kp + c * 16);
        kf1[c] = *(const bf16x8*)(kp + 32 * 1024 + c * 16);
        vf0[c] = *(const bf16x8*)(vp + c * 16);
        vf1[c] = *(const bf16x8*)(vp + 32 * T_SEQ + c * 16);
      }
    }
    tile_chain(kf0, kf1, vf0, vf1, qfB, zv, oB0, oB1, mB, lB, kv0, qwB, qB, hi);
    if (it < ntA)
      tile_chain(kf0, kf1, vf0, vf1, qfA, zv, oA0, oA1, mA, lA, kv0, qwA, qA, hi);
  }

  attn_epilogue(ctx + (size_t)(b * T_SEQ + qA) * 1024 + h * 64, oA0, oA1, lA, hi);
  attn_epilogue(ctx + (size_t)(b * T_SEQ + qB) * 1024 + h * 64, oB0, oB1, lB, hi);
}

// ---------------------------------------------------------------------------
extern "C" void kernel_launch(void* const* d_in, const int* in_sizes, int n_in,
                              void* d_out, int out_size, void* d_ws, size_t ws_size,
                              hipStream_t stream)
{
  (void)in_sizes; (void)n_in; (void)out_size; (void)ws_size;
  const float* x  = (const float*)d_in[0];
  // d_in[1] = causal mask (triu, k=1) — structure is known, not read
  const float* WQ = (const float*)d_in[2];
  const float* bQ = (const float*)d_in[3];
  const float* WK = (const float*)d_in[4];
  const float* bK = (const float*)d_in[5];
  const float* WV = (const float*)d_in[6];
  const float* bV = (const float*)d_in[7];
  const float* WO = (const float*)d_in[8];
  const float* bO = (const float*)d_in[9];
  float* out = (float*)d_out;

  const size_t MB = 1024ull * 1024ull;
  char* w = (char*)d_ws;
  short* xb = (short*)(w);             // 16MB; reused as ctx after QKV GEMMs
  short* Wt = (short*)(w + 16 * MB);   // 8MB: WQt,WKt,WVt,WOt bf16 (contiguous)
  short* Qb = (short*)(w + 24 * MB);   // 16MB
  short* Kb = (short*)(w + 40 * MB);   // 16MB
  short* Vt = (short*)(w + 72 * MB);   // 16MB (written directly by gemm_qkv)
  short* ctx = xb;

  prep_kernel<<<dim3(32, 32, 8), 256, 0, stream>>>(WQ, WK, WV, WO, Wt, x, xb);

  const float qscale = 0.125f * 1.4426950408889634f;  // fold 1/sqrt(64) * log2(e)
  gemm_qkv<<<dim3(64, 24), 256, 0, stream>>>(xb, Wt, bQ, bK, bV, Qb, Kb, Vt, qscale);

  attn_fwd<<<dim3(512), 256, 0, stream>>>(Qb, Kb, Vt, ctx);

  gemm_bt<<<dim3(64, 8), 256, 0, stream>>>(ctx, Wt + 3ull * D_MODEL * D_MODEL, bO, out);
}